// Round 4
// baseline (984.728 us; speedup 1.0000x reference)
//
#include <hip/hip_runtime.h>
#include <stdint.h>

typedef __attribute__((ext_vector_type(4))) float f32x4;
typedef __attribute__((ext_vector_type(8))) __bf16 bf16x8;
typedef __attribute__((ext_vector_type(4))) uint16_t u16x4;

#define CDIM 1024
#define K3   3072
#define NKT  48        // K3 / 64
#define LSEQ 13
#define NTOK 4096

__device__ __forceinline__ uint16_t f2bf(float x){
  union { float f; uint32_t u; } c; c.f = x;
  uint32_t r = (c.u + 0x7FFFu + ((c.u >> 16) & 1u)) >> 16;
  return (uint16_t)r;
}
__device__ __forceinline__ float bf2f(uint16_t h){
  union { uint32_t u; float f; } c; c.u = ((uint32_t)h) << 16;
  return c.f;
}

__device__ __forceinline__ void async16(const void* g, void* l){
  __builtin_amdgcn_global_load_lds((__attribute__((address_space(1))) void*)(g),
                                   (__attribute__((address_space(3))) void*)(l), 16, 0, 0);
}

// ---------------- conversion kernels ----------------

__global__ void convert_W(const float* __restrict__ W, uint16_t* __restrict__ W3){
  int idx = blockIdx.x * 256 + threadIdx.x;
  int j = idx >> 8;
  int c4 = (idx & 255) * 4;
  float4 v = *(const float4*)(W + (size_t)j * CDIM + c4);
  u16x4 h, lo;
  h.x = f2bf(v.x); lo.x = f2bf(v.x - bf2f(h.x));
  h.y = f2bf(v.y); lo.y = f2bf(v.y - bf2f(h.y));
  h.z = f2bf(v.z); lo.z = f2bf(v.z - bf2f(h.z));
  h.w = f2bf(v.w); lo.w = f2bf(v.w - bf2f(h.w));
  uint16_t* r = W3 + (size_t)j * K3;
  *(u16x4*)(r + c4)        = h;
  *(u16x4*)(r + 1024 + c4) = h;
  *(u16x4*)(r + 2048 + c4) = lo;
}

__global__ void rope_table(float* __restrict__ cosT, float* __restrict__ sinT){
  int t = threadIdx.x;
  if (t < LSEQ * 32){
    int l = t >> 5, i = t & 31;
    float inv = 1.0f / powf(10000.0f, ((float)(2 * i)) / 64.0f);
    float a = (float)l * inv;
    cosT[t] = cosf(a);
    sinT[t] = sinf(a);
  }
}

__global__ void convert_A(const float* __restrict__ src, uint16_t* __restrict__ Ah,
                          uint16_t* __restrict__ Al, int n0){
  int idx = blockIdx.x * 256 + threadIdx.x;
  int row = idx >> 8;
  int c4 = (idx & 255) * 4;
  int nl = row / 13;
  int l  = row - nl * 13;
  float4 v = *(const float4*)(src + (size_t)l * (NTOK * CDIM) + (size_t)(n0 + nl) * CDIM + c4);
  u16x4 h, lo;
  h.x = f2bf(v.x); lo.x = f2bf(v.x - bf2f(h.x));
  h.y = f2bf(v.y); lo.y = f2bf(v.y - bf2f(h.y));
  h.z = f2bf(v.z); lo.z = f2bf(v.z - bf2f(h.z));
  h.w = f2bf(v.w); lo.w = f2bf(v.w - bf2f(h.w));
  *(u16x4*)(Ah + (size_t)row * CDIM + c4) = h;
  *(u16x4*)(Al + (size_t)row * CDIM + c4) = lo;
}

__global__ void convert_Aq(const float* __restrict__ src, uint16_t* __restrict__ Ah,
                           uint16_t* __restrict__ Al){
  int idx = blockIdx.x * 256 + threadIdx.x;
  int n = idx >> 8;
  int c4 = (idx & 255) * 4;
  float4 v = *(const float4*)(src + (size_t)12 * (NTOK * CDIM) + (size_t)n * CDIM + c4);
  u16x4 h, lo;
  h.x = f2bf(v.x); lo.x = f2bf(v.x - bf2f(h.x));
  h.y = f2bf(v.y); lo.y = f2bf(v.y - bf2f(h.y));
  h.z = f2bf(v.z); lo.z = f2bf(v.z - bf2f(h.z));
  h.w = f2bf(v.w); lo.w = f2bf(v.w - bf2f(h.w));
  *(u16x4*)(Ah + (size_t)n * CDIM + c4) = h;
  *(u16x4*)(Al + (size_t)n * CDIM + c4) = lo;
}

// ---------------- 128x128 bf16x3 GEMM (2-barrier structure) — Q and O projections ----------------
__global__ __launch_bounds__(256, 2)
void gemm_x3(const uint16_t* __restrict__ Ahi, const uint16_t* __restrict__ Alo,
             const uint16_t* __restrict__ B3, float* __restrict__ Cout)
{
  __shared__ __align__(16) uint16_t sA[128 * 64];
  __shared__ __align__(16) uint16_t sB[128 * 64];
  const int tid  = threadIdx.x;
  const int lane = tid & 63;
  const int wave = tid >> 6;
  const int arow0 = blockIdx.x * 128;
  const int bcol0 = blockIdx.y * 128;
  const int wr = (wave >> 1) * 64;
  const int wc = (wave & 1) * 64;

  const f32x4 fzero = {0.f, 0.f, 0.f, 0.f};
  f32x4 acc[4][4];
#pragma unroll
  for (int i = 0; i < 4; ++i)
#pragma unroll
    for (int j = 0; j < 4; ++j)
      acc[i][j] = fzero;

  size_t aOff[4], bOff[4];
  int ldsOff[4];
#pragma unroll
  for (int i = 0; i < 4; ++i){
    int o = i * 256 + tid;
    int row = o >> 3;
    int ss = (o & 7) ^ (row & 7);
    aOff[i] = (size_t)(arow0 + row) * CDIM + ss * 8;
    bOff[i] = (size_t)(bcol0 + row) * K3 + ss * 8;
    ldsOff[i] = (i * 256 + wave * 64) * 16;
  }

  int aRd[2][4], bRd[2][4];
#pragma unroll
  for (int ks = 0; ks < 2; ++ks){
    int sw = ((lane >> 4) + ks * 4) ^ (lane & 7);
#pragma unroll
    for (int mi = 0; mi < 4; ++mi){
      aRd[ks][mi] = (wr + mi * 16 + (lane & 15)) * 128 + sw * 16;
      bRd[ks][mi] = (wc + mi * 16 + (lane & 15)) * 128 + sw * 16;
    }
  }

  const char* sAc = (const char*)sA;
  const char* sBc = (const char*)sB;

  for (int step = 0; step < NKT; ++step){
    const int kv0 = step * 64;
    const uint16_t* Abase = ((kv0 >> 10) == 1) ? Alo : Ahi;
    const int kr0 = kv0 & 1023;
#pragma unroll
    for (int i = 0; i < 4; ++i){
      async16(Abase + aOff[i] + kr0, (char*)sA + ldsOff[i]);
      async16(B3    + bOff[i] + kv0, (char*)sB + ldsOff[i]);
    }
    __syncthreads();
#pragma unroll
    for (int ks = 0; ks < 2; ++ks){
      bf16x8 af[4], bfr[4];
#pragma unroll
      for (int mi = 0; mi < 4; ++mi) af[mi]  = *(const bf16x8*)(sAc + aRd[ks][mi]);
#pragma unroll
      for (int ni = 0; ni < 4; ++ni) bfr[ni] = *(const bf16x8*)(sBc + bRd[ks][ni]);
#pragma unroll
      for (int mi = 0; mi < 4; ++mi)
#pragma unroll
        for (int ni = 0; ni < 4; ++ni)
          acc[mi][ni] = __builtin_amdgcn_mfma_f32_16x16x32_bf16(af[mi], bfr[ni], acc[mi][ni], 0, 0, 0);
    }
    __syncthreads();
  }

#pragma unroll
  for (int mi = 0; mi < 4; ++mi){
    const int row = arow0 + wr + mi * 16 + (lane >> 4) * 4;
#pragma unroll
    for (int r = 0; r < 4; ++r){
      float* crow = Cout + (size_t)(row + r) * CDIM + bcol0 + wc + (lane & 15);
#pragma unroll
      for (int ni = 0; ni < 4; ++ni)
        crow[ni * 16] = acc[mi][ni][r];
    }
  }
}

// ---------------- 256x256 8-phase bf16x3 GEMM (T3+T4+T5) — K and V projections ----------------
// 8 waves (2m x 4n), BK=64, 128KB LDS double-buffer. Per K-tile: 4 phases of
// {ds_read subtile | stage 1 half-tile | barrier | setprio+16 MFMA | barrier}.
// Counted vmcnt(6) once per K-tile (3 half-tiles = 6 loads/wave in flight).
// Region-retire invariant: B halves last-read phase 0 (staged ph1/ph2),
// A halves last-read phase 2 + explicit lgkmcnt(0) (A0 staged ph3, A1 staged next-ph0 into other buf).
__global__ __launch_bounds__(512, 1)
void gemm8_x3(const uint16_t* __restrict__ Ahi, const uint16_t* __restrict__ Alo,
              const uint16_t* __restrict__ B3, float* __restrict__ Cout)
{
  __shared__ __align__(16) char smem[131072];   // A: [0,64K), B: [64K,128K); 32K per buf
  const int tid  = threadIdx.x;
  const int lane = tid & 63;
  const int wave = tid >> 6;        // 0..7
  const int wave_m = wave >> 2;     // 0..1 -> 128 rows each
  const int wave_n = wave & 3;      // 0..3 -> 64 cols each
  const int arow0 = blockIdx.x * 256;
  const int bcol0 = blockIdx.y * 256;

  const f32x4 fzero = {0.f, 0.f, 0.f, 0.f};
  f32x4 acc[8][4];
#pragma unroll
  for (int i = 0; i < 8; ++i)
#pragma unroll
    for (int j = 0; j < 4; ++j)
      acc[i][j] = fzero;

  // fragment ds_read bases (bytes within one buffer); row&7 == lane&7 everywhere
  const int abase0 = (wave_m * 128 + (lane & 15)) * 128;
  const int bbase0 = (wave_n * 64  + (lane & 15)) * 128;
  const int s0 = (((lane >> 4))     ^ (lane & 7)) * 16;   // ks=0 swizzled slot
  const int s1 = ((4 + (lane >> 4)) ^ (lane & 7)) * 16;   // ks=1

  // staging offsets: unit u = h*1024 + (wave*2+j)*64 + lane  (1 operand-tile = 2048 units)
  size_t aU[2][2], bU[2][2];
  int ldsU[2][2];
#pragma unroll
  for (int h = 0; h < 2; ++h)
#pragma unroll
    for (int j = 0; j < 2; ++j){
      int u = h * 1024 + (wave * 2 + j) * 64 + lane;
      int row = u >> 3;
      int ss = (u & 7) ^ (row & 7);          // pre-swizzled source slot (rule #21)
      aU[h][j] = (size_t)(arow0 + row) * CDIM + ss * 8;
      bU[h][j] = (size_t)(bcol0 + row) * K3 + ss * 8;
      ldsU[h][j] = (h * 1024 + (wave * 2 + j) * 64) * 16;   // wave-uniform dest
    }

  auto stA = [&](int h, int tt, int dsel){
    const uint16_t* base = ((tt >> 4) == 1) ? Alo : Ahi;   // x3 phase: hi,lo,hi
    const int kr0 = (tt * 64) & 1023;
    async16(base + aU[h][0] + kr0, smem + dsel + ldsU[h][0]);
    async16(base + aU[h][1] + kr0, smem + dsel + ldsU[h][1]);
  };
  auto stB = [&](int h, int tt, int dsel){
    const int k0 = tt * 64;
    async16(B3 + bU[h][0] + k0, smem + 65536 + dsel + ldsU[h][0]);
    async16(B3 + bU[h][1] + k0, smem + 65536 + dsel + ldsU[h][1]);
  };

#define RDA(dst, M, As) { dst[0] = *(const bf16x8*)((As) + abase0 + (M)*2048 + s0); \
                          dst[1] = *(const bf16x8*)((As) + abase0 + (M)*2048 + s1); }
#define MM(MI, AF) { _Pragma("unroll") for (int n = 0; n < 4; ++n){ \
    acc[MI][n] = __builtin_amdgcn_mfma_f32_16x16x32_bf16(AF[0], bf[n][0], acc[MI][n], 0, 0, 0); \
    acc[MI][n] = __builtin_amdgcn_mfma_f32_16x16x32_bf16(AF[1], bf[n][1], acc[MI][n], 0, 0, 0); } }

  // prologue: tile0 {B0,B1,A0,A1} -> buf0; tile1 {B0,B1,A0} -> buf1  (A1[1] comes in t=0 phase0)
  stB(0, 0, 0);     stB(1, 0, 0);     stA(0, 0, 0);     stA(1, 0, 0);
  stB(0, 1, 32768); stB(1, 1, 32768); stA(0, 1, 32768);
  asm volatile("s_waitcnt vmcnt(6)" ::: "memory");     // tile0 fully landed
  __builtin_amdgcn_sched_barrier(0);
  __builtin_amdgcn_s_barrier();

#pragma unroll 2
  for (int t = 0; t < NKT; ++t){
    const int sel  = (t & 1) * 32768;
    const int seln = 32768 - sel;
    const char* As = smem + sel;
    const char* Bs = smem + 65536 + sel;

    bf16x8 bf[4][2], a0[2], a1[2], a2[2], a3[2], a4[2], a5[2], a6[2], a7[2];

    // ---- phase 0: read all B (8) + A m0,m1 (4); stage A1[t+1] -> other buf ----
#pragma unroll
    for (int n = 0; n < 4; ++n){
      bf[n][0] = *(const bf16x8*)(Bs + bbase0 + n * 2048 + s0);
      bf[n][1] = *(const bf16x8*)(Bs + bbase0 + n * 2048 + s1);
    }
    RDA(a0, 0, As); RDA(a1, 1, As);
    if (t + 1 < NKT) stA(1, t + 1, seln);
    __builtin_amdgcn_s_barrier();
    __builtin_amdgcn_s_setprio(1);
    MM(0, a0); MM(1, a1);
    __builtin_amdgcn_s_setprio(0);
    __builtin_amdgcn_s_barrier();

    // ---- phase 1: read A m2..m5 (8); stage B0[t+2] -> this buf ----
    RDA(a2, 2, As); RDA(a3, 3, As); RDA(a4, 4, As); RDA(a5, 5, As);
    if (t + 2 < NKT) stB(0, t + 2, sel);
    __builtin_amdgcn_s_barrier();
    __builtin_amdgcn_s_setprio(1);
    MM(2, a2); MM(3, a3);
    __builtin_amdgcn_s_setprio(0);
    __builtin_amdgcn_s_barrier();

    // ---- phase 2: read A m6,m7 (4); stage B1[t+2] ----
    RDA(a6, 6, As); RDA(a7, 7, As);
    if (t + 2 < NKT) stB(1, t + 2, sel);
    __builtin_amdgcn_s_barrier();
    __builtin_amdgcn_s_setprio(1);
    MM(4, a4); MM(5, a5);
    __builtin_amdgcn_s_setprio(0);
    asm volatile("s_waitcnt lgkmcnt(0)" ::: "memory");  // a6,a7 in-register before A0 restage
    __builtin_amdgcn_sched_barrier(0);
    __builtin_amdgcn_s_barrier();

    // ---- phase 3: stage A0[t+2]; counted vmcnt at K-tile boundary ----
    if (t + 2 < NKT) stA(0, t + 2, sel);
    if (t <= NKT - 3) { asm volatile("s_waitcnt vmcnt(6)" ::: "memory"); }
    else              { asm volatile("s_waitcnt vmcnt(0)" ::: "memory"); }
    __builtin_amdgcn_sched_barrier(0);
    __builtin_amdgcn_s_barrier();
    __builtin_amdgcn_s_setprio(1);
    MM(6, a6); MM(7, a7);
    __builtin_amdgcn_s_setprio(0);
    __builtin_amdgcn_s_barrier();
  }
#undef RDA
#undef MM

#pragma unroll
  for (int mi = 0; mi < 8; ++mi){
    const int row = arow0 + wave_m * 128 + mi * 16 + (lane >> 4) * 4;
#pragma unroll
    for (int r = 0; r < 4; ++r){
      float* crow = Cout + (size_t)(row + r) * CDIM + bcol0 + wave_n * 64 + (lane & 15);
#pragma unroll
      for (int ni = 0; ni < 4; ++ni)
        crow[ni * 16] = acc[mi][ni][r];
    }
  }
}

// ---------------- fused RoPE + attention (l = 12 query only) ----------------
__global__ void attn_kernel(const float* __restrict__ Kb, const float* __restrict__ Vb,
                            const float* __restrict__ q, const float* __restrict__ cosT,
                            const float* __restrict__ sinT, uint16_t* __restrict__ ohi,
                            uint16_t* __restrict__ olo, int n0)
{
  int wid  = blockIdx.x * 4 + (threadIdx.x >> 6);
  int lane = threadIdx.x & 63;
  int nl = wid >> 4;
  int h  = wid & 15;
  int d = lane, i = d & 31;

  size_t qoff = (size_t)(n0 + nl) * CDIM + h * 64 + d;
  float qv = q[qoff];
  float qp = __shfl_xor(qv, 32);
  float cq = cosT[12 * 32 + i], sq = sinT[12 * 32 + i];
  float qr = (d < 32) ? (qv * cq - qp * sq) : (qv * cq + qp * sq);

  const float* Kp = Kb + (size_t)nl * (LSEQ * CDIM) + h * 64 + d;
  const float* Vp = Vb + (size_t)nl * (LSEQ * CDIM) + h * 64 + d;

  float s[LSEQ];
#pragma unroll
  for (int m = 0; m < LSEQ; ++m){
    float kv = Kp[m * CDIM];
    float kp = __shfl_xor(kv, 32);
    float cm = cosT[m * 32 + i], sm = sinT[m * 32 + i];
    float kr = (d < 32) ? (kv * cm - kp * sm) : (kv * cm + kp * sm);
    float p = qr * kr;
    p += __shfl_xor(p, 32); p += __shfl_xor(p, 16); p += __shfl_xor(p, 8);
    p += __shfl_xor(p, 4);  p += __shfl_xor(p, 2);  p += __shfl_xor(p, 1);
    s[m] = p * 0.125f;
  }
  float mx = s[0];
#pragma unroll
  for (int m = 1; m < LSEQ; ++m) mx = fmaxf(mx, s[m]);
  float sum = 0.f;
#pragma unroll
  for (int m = 0; m < LSEQ; ++m){ s[m] = expf(s[m] - mx); sum += s[m]; }
  float inv = 1.0f / sum;
  float o = 0.f;
#pragma unroll
  for (int m = 0; m < LSEQ; ++m) o += s[m] * Vp[m * CDIM];
  o *= inv;
  uint16_t hb = f2bf(o);
  uint16_t lb = f2bf(o - bf2f(hb));
  ohi[qoff] = hb;
  olo[qoff] = lb;
}

// ---------------- host ----------------
extern "C" void kernel_launch(void* const* d_in, const int* in_sizes, int n_in,
                              void* d_out, int out_size, void* d_ws, size_t ws_size,
                              hipStream_t stream)
{
  (void)in_sizes; (void)n_in; (void)out_size;
  const float* src = (const float*)d_in[0];
  const float* Wq  = (const float*)d_in[1];
  const float* Wk  = (const float*)d_in[2];
  const float* Wv  = (const float*)d_in[3];
  const float* Wo  = (const float*)d_in[4];
  float* out = (float*)d_out;

  // adaptive chunk (cn*13 must divide by 256 -> cn >= 256; poison fill suggests ws ~852MB -> cn=4096)
  int cn = 4096;
  while (cn > 256 && (75506000ull + (size_t)cn * 159744ull) > ws_size) cn >>= 1;
  const int nchunks = NTOK / cn;

  char* p = (char*)d_ws;
  auto carve = [&](size_t bytes) -> void* {
    void* r = (void*)p; p += (bytes + 255) & ~(size_t)255; return r;
  };
  uint16_t* W3q = (uint16_t*)carve((size_t)CDIM * K3 * 2);
  uint16_t* W3k = (uint16_t*)carve((size_t)CDIM * K3 * 2);
  uint16_t* W3v = (uint16_t*)carve((size_t)CDIM * K3 * 2);
  uint16_t* W3o = (uint16_t*)carve((size_t)CDIM * K3 * 2);
  float* cosT = (float*)carve(LSEQ * 32 * 4);
  float* sinT = (float*)carve(LSEQ * 32 * 4);
  uint16_t* Aqh = (uint16_t*)carve((size_t)NTOK * CDIM * 2);
  uint16_t* Aql = (uint16_t*)carve((size_t)NTOK * CDIM * 2);
  float* qbuf   = (float*)carve((size_t)NTOK * CDIM * 4);
  uint16_t* ohi = (uint16_t*)carve((size_t)NTOK * CDIM * 2);
  uint16_t* olo = (uint16_t*)carve((size_t)NTOK * CDIM * 2);
  uint16_t* Ah  = (uint16_t*)carve((size_t)cn * LSEQ * CDIM * 2);
  uint16_t* Al  = (uint16_t*)carve((size_t)cn * LSEQ * CDIM * 2);
  float* Kb     = (float*)carve((size_t)cn * LSEQ * CDIM * 4);
  float* Vb     = (float*)carve((size_t)cn * LSEQ * CDIM * 4);

  convert_W<<<1024, 256, 0, stream>>>(Wq, W3q);
  convert_W<<<1024, 256, 0, stream>>>(Wk, W3k);
  convert_W<<<1024, 256, 0, stream>>>(Wv, W3v);
  convert_W<<<1024, 256, 0, stream>>>(Wo, W3o);
  rope_table<<<1, 512, 0, stream>>>(cosT, sinT);
  convert_Aq<<<NTOK, 256, 0, stream>>>(src, Aqh, Aql);
  gemm_x3<<<dim3(NTOK / 128, 8), 256, 0, stream>>>(Aqh, Aql, W3q, qbuf);

  for (int c = 0; c < nchunks; ++c){
    const int mt = cn * LSEQ / 256;       // 256-row tiles
    convert_A<<<cn * LSEQ, 256, 0, stream>>>(src, Ah, Al, c * cn);
    gemm8_x3<<<dim3(mt, 4), 512, 0, stream>>>(Ah, Al, W3k, Kb);
    gemm8_x3<<<dim3(mt, 4), 512, 0, stream>>>(Ah, Al, W3v, Vb);
    attn_kernel<<<cn * 4, 256, 0, stream>>>(Kb, Vb, qbuf, cosT, sinT, ohi, olo, c * cn);
  }
  gemm_x3<<<dim3(NTOK / 128, 8), 256, 0, stream>>>(ohi, olo, W3o, out);
}

// Round 5
// 927.603 us; speedup vs baseline: 1.0616x; 1.0616x over previous
//
#include <hip/hip_runtime.h>
#include <stdint.h>

typedef __attribute__((ext_vector_type(4))) float f32x4;
typedef __attribute__((ext_vector_type(8))) __bf16 bf16x8;
typedef __attribute__((ext_vector_type(4))) uint16_t u16x4;

#define CDIM 1024
#define K3   3072
#define NKT  48        // K3 / 64
#define LSEQ 13
#define NTOK 4096

__device__ __forceinline__ uint16_t f2bf(float x){
  union { float f; uint32_t u; } c; c.f = x;
  uint32_t r = (c.u + 0x7FFFu + ((c.u >> 16) & 1u)) >> 16;
  return (uint16_t)r;
}
__device__ __forceinline__ float bf2f(uint16_t h){
  union { uint32_t u; float f; } c; c.u = ((uint32_t)h) << 16;
  return c.f;
}

__device__ __forceinline__ void async16(const void* g, void* l){
  __builtin_amdgcn_global_load_lds((__attribute__((address_space(1))) void*)(g),
                                   (__attribute__((address_space(3))) void*)(l), 16, 0, 0);
}

// ---------------- conversion kernels ----------------

__global__ void convert_W(const float* __restrict__ W, uint16_t* __restrict__ W3){
  int idx = blockIdx.x * 256 + threadIdx.x;
  int j = idx >> 8;
  int c4 = (idx & 255) * 4;
  float4 v = *(const float4*)(W + (size_t)j * CDIM + c4);
  u16x4 h, lo;
  h.x = f2bf(v.x); lo.x = f2bf(v.x - bf2f(h.x));
  h.y = f2bf(v.y); lo.y = f2bf(v.y - bf2f(h.y));
  h.z = f2bf(v.z); lo.z = f2bf(v.z - bf2f(h.z));
  h.w = f2bf(v.w); lo.w = f2bf(v.w - bf2f(h.w));
  uint16_t* r = W3 + (size_t)j * K3;
  *(u16x4*)(r + c4)        = h;
  *(u16x4*)(r + 1024 + c4) = h;
  *(u16x4*)(r + 2048 + c4) = lo;
}

__global__ void rope_table(float* __restrict__ cosT, float* __restrict__ sinT){
  int t = threadIdx.x;
  if (t < LSEQ * 32){
    int l = t >> 5, i = t & 31;
    float inv = 1.0f / powf(10000.0f, ((float)(2 * i)) / 64.0f);
    float a = (float)l * inv;
    cosT[t] = cosf(a);
    sinT[t] = sinf(a);
  }
}

__global__ void convert_A(const float* __restrict__ src, uint16_t* __restrict__ Ah,
                          uint16_t* __restrict__ Al, int n0){
  int idx = blockIdx.x * 256 + threadIdx.x;
  int row = idx >> 8;
  int c4 = (idx & 255) * 4;
  int nl = row / 13;
  int l  = row - nl * 13;
  float4 v = *(const float4*)(src + (size_t)l * (NTOK * CDIM) + (size_t)(n0 + nl) * CDIM + c4);
  u16x4 h, lo;
  h.x = f2bf(v.x); lo.x = f2bf(v.x - bf2f(h.x));
  h.y = f2bf(v.y); lo.y = f2bf(v.y - bf2f(h.y));
  h.z = f2bf(v.z); lo.z = f2bf(v.z - bf2f(h.z));
  h.w = f2bf(v.w); lo.w = f2bf(v.w - bf2f(h.w));
  *(u16x4*)(Ah + (size_t)row * CDIM + c4) = h;
  *(u16x4*)(Al + (size_t)row * CDIM + c4) = lo;
}

__global__ void convert_Aq(const float* __restrict__ src, uint16_t* __restrict__ Ah,
                           uint16_t* __restrict__ Al){
  int idx = blockIdx.x * 256 + threadIdx.x;
  int n = idx >> 8;
  int c4 = (idx & 255) * 4;
  float4 v = *(const float4*)(src + (size_t)12 * (NTOK * CDIM) + (size_t)n * CDIM + c4);
  u16x4 h, lo;
  h.x = f2bf(v.x); lo.x = f2bf(v.x - bf2f(h.x));
  h.y = f2bf(v.y); lo.y = f2bf(v.y - bf2f(h.y));
  h.z = f2bf(v.z); lo.z = f2bf(v.z - bf2f(h.z));
  h.w = f2bf(v.w); lo.w = f2bf(v.w - bf2f(h.w));
  *(u16x4*)(Ah + (size_t)n * CDIM + c4) = h;
  *(u16x4*)(Al + (size_t)n * CDIM + c4) = lo;
}

// ---------------- 128x128 bf16x3 GEMM (2-barrier structure) — Q and O projections ----------------
__global__ __launch_bounds__(256, 2)
void gemm_x3(const uint16_t* __restrict__ Ahi, const uint16_t* __restrict__ Alo,
             const uint16_t* __restrict__ B3, float* __restrict__ Cout)
{
  __shared__ __align__(16) uint16_t sA[128 * 64];
  __shared__ __align__(16) uint16_t sB[128 * 64];
  const int tid  = threadIdx.x;
  const int lane = tid & 63;
  const int wave = tid >> 6;
  const int arow0 = blockIdx.x * 128;
  const int bcol0 = blockIdx.y * 128;
  const int wr = (wave >> 1) * 64;
  const int wc = (wave & 1) * 64;

  const f32x4 fzero = {0.f, 0.f, 0.f, 0.f};
  f32x4 acc[4][4];
#pragma unroll
  for (int i = 0; i < 4; ++i)
#pragma unroll
    for (int j = 0; j < 4; ++j)
      acc[i][j] = fzero;

  size_t aOff[4], bOff[4];
  int ldsOff[4];
#pragma unroll
  for (int i = 0; i < 4; ++i){
    int o = i * 256 + tid;
    int row = o >> 3;
    int ss = (o & 7) ^ (row & 7);
    aOff[i] = (size_t)(arow0 + row) * CDIM + ss * 8;
    bOff[i] = (size_t)(bcol0 + row) * K3 + ss * 8;
    ldsOff[i] = (i * 256 + wave * 64) * 16;
  }

  int aRd[2][4], bRd[2][4];
#pragma unroll
  for (int ks = 0; ks < 2; ++ks){
    int sw = ((lane >> 4) + ks * 4) ^ (lane & 7);
#pragma unroll
    for (int mi = 0; mi < 4; ++mi){
      aRd[ks][mi] = (wr + mi * 16 + (lane & 15)) * 128 + sw * 16;
      bRd[ks][mi] = (wc + mi * 16 + (lane & 15)) * 128 + sw * 16;
    }
  }

  const char* sAc = (const char*)sA;
  const char* sBc = (const char*)sB;

  for (int step = 0; step < NKT; ++step){
    const int kv0 = step * 64;
    const uint16_t* Abase = ((kv0 >> 10) == 1) ? Alo : Ahi;
    const int kr0 = kv0 & 1023;
#pragma unroll
    for (int i = 0; i < 4; ++i){
      async16(Abase + aOff[i] + kr0, (char*)sA + ldsOff[i]);
      async16(B3    + bOff[i] + kv0, (char*)sB + ldsOff[i]);
    }
    __syncthreads();
#pragma unroll
    for (int ks = 0; ks < 2; ++ks){
      bf16x8 af[4], bfr[4];
#pragma unroll
      for (int mi = 0; mi < 4; ++mi) af[mi]  = *(const bf16x8*)(sAc + aRd[ks][mi]);
#pragma unroll
      for (int ni = 0; ni < 4; ++ni) bfr[ni] = *(const bf16x8*)(sBc + bRd[ks][ni]);
#pragma unroll
      for (int mi = 0; mi < 4; ++mi)
#pragma unroll
        for (int ni = 0; ni < 4; ++ni)
          acc[mi][ni] = __builtin_amdgcn_mfma_f32_16x16x32_bf16(af[mi], bfr[ni], acc[mi][ni], 0, 0, 0);
    }
    __syncthreads();
  }

#pragma unroll
  for (int mi = 0; mi < 4; ++mi){
    const int row = arow0 + wr + mi * 16 + (lane >> 4) * 4;
#pragma unroll
    for (int r = 0; r < 4; ++r){
      float* crow = Cout + (size_t)(row + r) * CDIM + bcol0 + wc + (lane & 15);
#pragma unroll
      for (int ni = 0; ni < 4; ++ni)
        crow[ni * 16] = acc[mi][ni][r];
    }
  }
}

// ---------------- 256x256 8-phase bf16x3 GEMM, merged K|V B-panel ----------------
// grid (8 cols, Mt rows), x fastest: the 8 co-dispatched blocks of one row-tile
// round-robin onto the 8 XCDs (each XCD keeps one 1.5MB B column-panel L2-resident)
// and share the A row-tile through L3 -> A fetched from HBM once, not 8x.
// B3kv rows 0..1023 = K output cols, 1024..2047 = V output cols.
__global__ __launch_bounds__(512, 1)
void gemm8_kv(const uint16_t* __restrict__ Ahi, const uint16_t* __restrict__ Alo,
              const uint16_t* __restrict__ B3, float* __restrict__ Kout,
              float* __restrict__ Vout)
{
  __shared__ __align__(16) char smem[131072];   // A: [0,64K), B: [64K,128K); 32K per buf
  const int tid  = threadIdx.x;
  const int lane = tid & 63;
  const int wave = tid >> 6;        // 0..7
  const int wave_m = wave >> 2;     // 0..1 -> 128 rows each
  const int wave_n = wave & 3;      // 0..3 -> 64 cols each
  const int arow0 = blockIdx.y * 256;
  const int gcol  = blockIdx.x * 256;          // 0..1792 within [K|V] panel
  float* Cout = (gcol < 1024) ? Kout : Vout;
  const int bcol0 = gcol & 1023;

  const f32x4 fzero = {0.f, 0.f, 0.f, 0.f};
  f32x4 acc[8][4];
#pragma unroll
  for (int i = 0; i < 8; ++i)
#pragma unroll
    for (int j = 0; j < 4; ++j)
      acc[i][j] = fzero;

  // fragment ds_read bases (bytes within one buffer); row&7 == lane&7 everywhere
  const int abase0 = (wave_m * 128 + (lane & 15)) * 128;
  const int bbase0 = (wave_n * 64  + (lane & 15)) * 128;
  const int s0 = (((lane >> 4))     ^ (lane & 7)) * 16;   // ks=0 swizzled slot
  const int s1 = ((4 + (lane >> 4)) ^ (lane & 7)) * 16;   // ks=1

  // staging offsets: unit u = h*1024 + (wave*2+j)*64 + lane  (1 operand-tile = 2048 units)
  size_t aU[2][2], bU[2][2];
  int ldsU[2][2];
#pragma unroll
  for (int h = 0; h < 2; ++h)
#pragma unroll
    for (int j = 0; j < 2; ++j){
      int u = h * 1024 + (wave * 2 + j) * 64 + lane;
      int row = u >> 3;
      int ss = (u & 7) ^ (row & 7);          // pre-swizzled source slot (rule #21)
      aU[h][j] = (size_t)(arow0 + row) * CDIM + ss * 8;
      bU[h][j] = (size_t)(gcol  + row) * K3 + ss * 8;
      ldsU[h][j] = (h * 1024 + (wave * 2 + j) * 64) * 16;   // wave-uniform dest
    }

  auto stA = [&](int h, int tt, int dsel){
    const uint16_t* base = ((tt >> 4) == 1) ? Alo : Ahi;   // x3 phase: hi,lo,hi
    const int kr0 = (tt * 64) & 1023;
    async16(base + aU[h][0] + kr0, smem + dsel + ldsU[h][0]);
    async16(base + aU[h][1] + kr0, smem + dsel + ldsU[h][1]);
  };
  auto stB = [&](int h, int tt, int dsel){
    const int k0 = tt * 64;
    async16(B3 + bU[h][0] + k0, smem + 65536 + dsel + ldsU[h][0]);
    async16(B3 + bU[h][1] + k0, smem + 65536 + dsel + ldsU[h][1]);
  };

#define RDA(dst, M, As) { dst[0] = *(const bf16x8*)((As) + abase0 + (M)*2048 + s0); \
                          dst[1] = *(const bf16x8*)((As) + abase0 + (M)*2048 + s1); }
#define MM(MI, AF) { _Pragma("unroll") for (int n = 0; n < 4; ++n){ \
    acc[MI][n] = __builtin_amdgcn_mfma_f32_16x16x32_bf16(AF[0], bf[n][0], acc[MI][n], 0, 0, 0); \
    acc[MI][n] = __builtin_amdgcn_mfma_f32_16x16x32_bf16(AF[1], bf[n][1], acc[MI][n], 0, 0, 0); } }

  // prologue: tile0 {B0,B1,A0,A1} -> buf0; tile1 {B0,B1,A0} -> buf1  (A1[1] comes in t=0 phase0)
  stB(0, 0, 0);     stB(1, 0, 0);     stA(0, 0, 0);     stA(1, 0, 0);
  stB(0, 1, 32768); stB(1, 1, 32768); stA(0, 1, 32768);
  asm volatile("s_waitcnt vmcnt(6)" ::: "memory");     // tile0 fully landed
  __builtin_amdgcn_sched_barrier(0);
  __builtin_amdgcn_s_barrier();

#pragma unroll 2
  for (int t = 0; t < NKT; ++t){
    const int sel  = (t & 1) * 32768;
    const int seln = 32768 - sel;
    const char* As = smem + sel;
    const char* Bs = smem + 65536 + sel;

    bf16x8 bf[4][2], a0[2], a1[2], a2[2], a3[2], a4[2], a5[2], a6[2], a7[2];

    // ---- phase 0: read all B (8) + A m0,m1 (4); stage A1[t+1] -> other buf ----
#pragma unroll
    for (int n = 0; n < 4; ++n){
      bf[n][0] = *(const bf16x8*)(Bs + bbase0 + n * 2048 + s0);
      bf[n][1] = *(const bf16x8*)(Bs + bbase0 + n * 2048 + s1);
    }
    RDA(a0, 0, As); RDA(a1, 1, As);
    if (t + 1 < NKT) stA(1, t + 1, seln);
    __builtin_amdgcn_s_barrier();
    __builtin_amdgcn_s_setprio(1);
    MM(0, a0); MM(1, a1);
    __builtin_amdgcn_s_setprio(0);
    __builtin_amdgcn_s_barrier();

    // ---- phase 1: read A m2..m5 (8); stage B0[t+2] -> this buf ----
    RDA(a2, 2, As); RDA(a3, 3, As); RDA(a4, 4, As); RDA(a5, 5, As);
    if (t + 2 < NKT) stB(0, t + 2, sel);
    __builtin_amdgcn_s_barrier();
    __builtin_amdgcn_s_setprio(1);
    MM(2, a2); MM(3, a3);
    __builtin_amdgcn_s_setprio(0);
    __builtin_amdgcn_s_barrier();

    // ---- phase 2: read A m6,m7 (4); stage B1[t+2] ----
    RDA(a6, 6, As); RDA(a7, 7, As);
    if (t + 2 < NKT) stB(1, t + 2, sel);
    __builtin_amdgcn_s_barrier();
    __builtin_amdgcn_s_setprio(1);
    MM(4, a4); MM(5, a5);
    __builtin_amdgcn_s_setprio(0);
    asm volatile("s_waitcnt lgkmcnt(0)" ::: "memory");  // a6,a7 in-register before A0 restage
    __builtin_amdgcn_sched_barrier(0);
    __builtin_amdgcn_s_barrier();

    // ---- phase 3: stage A0[t+2]; counted vmcnt at K-tile boundary ----
    if (t + 2 < NKT) stA(0, t + 2, sel);
    if (t <= NKT - 3) { asm volatile("s_waitcnt vmcnt(6)" ::: "memory"); }
    else              { asm volatile("s_waitcnt vmcnt(0)" ::: "memory"); }
    __builtin_amdgcn_sched_barrier(0);
    __builtin_amdgcn_s_barrier();
    __builtin_amdgcn_s_setprio(1);
    MM(6, a6); MM(7, a7);
    __builtin_amdgcn_s_setprio(0);
    __builtin_amdgcn_s_barrier();
  }
#undef RDA
#undef MM

#pragma unroll
  for (int mi = 0; mi < 8; ++mi){
    const int row = arow0 + wave_m * 128 + mi * 16 + (lane >> 4) * 4;
#pragma unroll
    for (int r = 0; r < 4; ++r){
      float* crow = Cout + (size_t)(row + r) * CDIM + bcol0 + wave_n * 64 + (lane & 15);
#pragma unroll
      for (int ni = 0; ni < 4; ++ni)
        crow[ni * 16] = acc[mi][ni][r];
    }
  }
}

// ---------------- fused RoPE + attention (l = 12 query only) ----------------
__global__ void attn_kernel(const float* __restrict__ Kb, const float* __restrict__ Vb,
                            const float* __restrict__ q, const float* __restrict__ cosT,
                            const float* __restrict__ sinT, uint16_t* __restrict__ ohi,
                            uint16_t* __restrict__ olo, int n0)
{
  int wid  = blockIdx.x * 4 + (threadIdx.x >> 6);
  int lane = threadIdx.x & 63;
  int nl = wid >> 4;
  int h  = wid & 15;
  int d = lane, i = d & 31;

  size_t qoff = (size_t)(n0 + nl) * CDIM + h * 64 + d;
  float qv = q[qoff];
  float qp = __shfl_xor(qv, 32);
  float cq = cosT[12 * 32 + i], sq = sinT[12 * 32 + i];
  float qr = (d < 32) ? (qv * cq - qp * sq) : (qv * cq + qp * sq);

  const float* Kp = Kb + (size_t)nl * (LSEQ * CDIM) + h * 64 + d;
  const float* Vp = Vb + (size_t)nl * (LSEQ * CDIM) + h * 64 + d;

  float s[LSEQ];
#pragma unroll
  for (int m = 0; m < LSEQ; ++m){
    float kv = Kp[m * CDIM];
    float kp = __shfl_xor(kv, 32);
    float cm = cosT[m * 32 + i], sm = sinT[m * 32 + i];
    float kr = (d < 32) ? (kv * cm - kp * sm) : (kv * cm + kp * sm);
    float p = qr * kr;
    p += __shfl_xor(p, 32); p += __shfl_xor(p, 16); p += __shfl_xor(p, 8);
    p += __shfl_xor(p, 4);  p += __shfl_xor(p, 2);  p += __shfl_xor(p, 1);
    s[m] = p * 0.125f;
  }
  float mx = s[0];
#pragma unroll
  for (int m = 1; m < LSEQ; ++m) mx = fmaxf(mx, s[m]);
  float sum = 0.f;
#pragma unroll
  for (int m = 0; m < LSEQ; ++m){ s[m] = expf(s[m] - mx); sum += s[m]; }
  float inv = 1.0f / sum;
  float o = 0.f;
#pragma unroll
  for (int m = 0; m < LSEQ; ++m) o += s[m] * Vp[m * CDIM];
  o *= inv;
  uint16_t hb = f2bf(o);
  uint16_t lb = f2bf(o - bf2f(hb));
  ohi[qoff] = hb;
  olo[qoff] = lb;
}

// ---------------- host ----------------
extern "C" void kernel_launch(void* const* d_in, const int* in_sizes, int n_in,
                              void* d_out, int out_size, void* d_ws, size_t ws_size,
                              hipStream_t stream)
{
  (void)in_sizes; (void)n_in; (void)out_size;
  const float* src = (const float*)d_in[0];
  const float* Wq  = (const float*)d_in[1];
  const float* Wk  = (const float*)d_in[2];
  const float* Wv  = (const float*)d_in[3];
  const float* Wo  = (const float*)d_in[4];
  float* out = (float*)d_out;

  // adaptive chunk (cn*13 must divide by 256 -> cn multiple of 256; ws ~852MB -> cn=4096)
  int cn = 4096;
  while (cn > 256 && (81800000ull + (size_t)cn * 159744ull) > ws_size) cn >>= 1;
  const int nchunks = NTOK / cn;

  char* p = (char*)d_ws;
  auto carve = [&](size_t bytes) -> void* {
    void* r = (void*)p; p += (bytes + 255) & ~(size_t)255; return r;
  };
  uint16_t* W3q  = (uint16_t*)carve((size_t)CDIM * K3 * 2);
  uint16_t* W3kv = (uint16_t*)carve((size_t)2 * CDIM * K3 * 2);   // rows 0..1023 K, 1024..2047 V
  uint16_t* W3o  = (uint16_t*)carve((size_t)CDIM * K3 * 2);
  float* cosT = (float*)carve(LSEQ * 32 * 4);
  float* sinT = (float*)carve(LSEQ * 32 * 4);
  uint16_t* Aqh = (uint16_t*)carve((size_t)NTOK * CDIM * 2);
  uint16_t* Aql = (uint16_t*)carve((size_t)NTOK * CDIM * 2);
  float* qbuf   = (float*)carve((size_t)NTOK * CDIM * 4);
  uint16_t* ohi = (uint16_t*)carve((size_t)NTOK * CDIM * 2);
  uint16_t* olo = (uint16_t*)carve((size_t)NTOK * CDIM * 2);
  uint16_t* Ah  = (uint16_t*)carve((size_t)cn * LSEQ * CDIM * 2);
  uint16_t* Al  = (uint16_t*)carve((size_t)cn * LSEQ * CDIM * 2);
  float* Kb     = (float*)carve((size_t)cn * LSEQ * CDIM * 4);
  float* Vb     = (float*)carve((size_t)cn * LSEQ * CDIM * 4);

  convert_W<<<1024, 256, 0, stream>>>(Wq, W3q);
  convert_W<<<1024, 256, 0, stream>>>(Wk, W3kv);
  convert_W<<<1024, 256, 0, stream>>>(Wv, W3kv + (size_t)CDIM * K3);
  convert_W<<<1024, 256, 0, stream>>>(Wo, W3o);
  rope_table<<<1, 512, 0, stream>>>(cosT, sinT);
  convert_Aq<<<NTOK, 256, 0, stream>>>(src, Aqh, Aql);
  gemm_x3<<<dim3(NTOK / 128, 8), 256, 0, stream>>>(Aqh, Aql, W3q, qbuf);

  for (int c = 0; c < nchunks; ++c){
    const int mt = cn * LSEQ / 256;       // 256-row tiles
    convert_A<<<cn * LSEQ, 256, 0, stream>>>(src, Ah, Al, c * cn);
    gemm8_kv<<<dim3(8, mt), 512, 0, stream>>>(Ah, Al, W3kv, Kb, Vb);
    attn_kernel<<<cn * 4, 256, 0, stream>>>(Kb, Vb, qbuf, cosT, sinT, ohi, olo, c * cn);
  }
  gemm_x3<<<dim3(NTOK / 128, 8), 256, 0, stream>>>(ohi, olo, W3o, out);
}

// Round 6
// 797.913 us; speedup vs baseline: 1.2341x; 1.1625x over previous
//
#include <hip/hip_runtime.h>
#include <stdint.h>

typedef __attribute__((ext_vector_type(4))) float f32x4;
typedef __attribute__((ext_vector_type(8))) __bf16 bf16x8;
typedef __attribute__((ext_vector_type(4))) uint16_t u16x4;

#define CDIM 1024
#define K3   3072
#define LSEQ 13
#define NTOK 4096

__device__ __forceinline__ uint16_t f2bf(float x){
  union { float f; uint32_t u; } c; c.f = x;
  uint32_t r = (c.u + 0x7FFFu + ((c.u >> 16) & 1u)) >> 16;
  return (uint16_t)r;
}
__device__ __forceinline__ float bf2f(uint16_t h){
  union { uint32_t u; float f; } c; c.u = ((uint32_t)h) << 16;
  return c.f;
}

__device__ __forceinline__ void async16(const void* g, void* l){
  __builtin_amdgcn_global_load_lds((__attribute__((address_space(1))) void*)(g),
                                   (__attribute__((address_space(3))) void*)(l), 16, 0, 0);
}

// ---------------- conversion kernels ----------------

// W fp32 -> [1024][3072] bf16 = [hi | hi | lo]   (x3 virtual-K layout)
__global__ void convert_W(const float* __restrict__ W, uint16_t* __restrict__ W3){
  int idx = blockIdx.x * 256 + threadIdx.x;
  int j = idx >> 8;
  int c4 = (idx & 255) * 4;
  float4 v = *(const float4*)(W + (size_t)j * CDIM + c4);
  u16x4 h, lo;
  h.x = f2bf(v.x); lo.x = f2bf(v.x - bf2f(h.x));
  h.y = f2bf(v.y); lo.y = f2bf(v.y - bf2f(h.y));
  h.z = f2bf(v.z); lo.z = f2bf(v.z - bf2f(h.z));
  h.w = f2bf(v.w); lo.w = f2bf(v.w - bf2f(h.w));
  uint16_t* r = W3 + (size_t)j * K3;
  *(u16x4*)(r + c4)        = h;
  *(u16x4*)(r + 1024 + c4) = h;
  *(u16x4*)(r + 2048 + c4) = lo;
}

// W fp32 -> [1024][1024] bf16 hi only   (x1 layout, V projection)
__global__ void convert_W1(const float* __restrict__ W, uint16_t* __restrict__ W1){
  int idx = blockIdx.x * 256 + threadIdx.x;
  int j = idx >> 8;
  int c4 = (idx & 255) * 4;
  float4 v = *(const float4*)(W + (size_t)j * CDIM + c4);
  u16x4 h;
  h.x = f2bf(v.x); h.y = f2bf(v.y); h.z = f2bf(v.z); h.w = f2bf(v.w);
  *(u16x4*)(W1 + (size_t)j * CDIM + c4) = h;
}

__global__ void rope_table(float* __restrict__ cosT, float* __restrict__ sinT){
  int t = threadIdx.x;
  if (t < LSEQ * 32){
    int l = t >> 5, i = t & 31;
    float inv = 1.0f / powf(10000.0f, ((float)(2 * i)) / 64.0f);
    float a = (float)l * inv;
    cosT[t] = cosf(a);
    sinT[t] = sinf(a);
  }
}

__global__ void convert_A(const float* __restrict__ src, uint16_t* __restrict__ Ah,
                          uint16_t* __restrict__ Al, int n0){
  int idx = blockIdx.x * 256 + threadIdx.x;
  int row = idx >> 8;
  int c4 = (idx & 255) * 4;
  int nl = row / 13;
  int l  = row - nl * 13;
  float4 v = *(const float4*)(src + (size_t)l * (NTOK * CDIM) + (size_t)(n0 + nl) * CDIM + c4);
  u16x4 h, lo;
  h.x = f2bf(v.x); lo.x = f2bf(v.x - bf2f(h.x));
  h.y = f2bf(v.y); lo.y = f2bf(v.y - bf2f(h.y));
  h.z = f2bf(v.z); lo.z = f2bf(v.z - bf2f(h.z));
  h.w = f2bf(v.w); lo.w = f2bf(v.w - bf2f(h.w));
  *(u16x4*)(Ah + (size_t)row * CDIM + c4) = h;
  *(u16x4*)(Al + (size_t)row * CDIM + c4) = lo;
}

__global__ void convert_Aq(const float* __restrict__ src, uint16_t* __restrict__ Ah,
                           uint16_t* __restrict__ Al){
  int idx = blockIdx.x * 256 + threadIdx.x;
  int n = idx >> 8;
  int c4 = (idx & 255) * 4;
  float4 v = *(const float4*)(src + (size_t)12 * (NTOK * CDIM) + (size_t)n * CDIM + c4);
  u16x4 h, lo;
  h.x = f2bf(v.x); lo.x = f2bf(v.x - bf2f(h.x));
  h.y = f2bf(v.y); lo.y = f2bf(v.y - bf2f(h.y));
  h.z = f2bf(v.z); lo.z = f2bf(v.z - bf2f(h.z));
  h.w = f2bf(v.w); lo.w = f2bf(v.w - bf2f(h.w));
  *(u16x4*)(Ah + (size_t)n * CDIM + c4) = h;
  *(u16x4*)(Al + (size_t)n * CDIM + c4) = lo;
}

// ---------------- 128x128 bf16x3 GEMM (2-barrier structure) — Q and O projections ----------------
__global__ __launch_bounds__(256, 2)
void gemm_x3(const uint16_t* __restrict__ Ahi, const uint16_t* __restrict__ Alo,
             const uint16_t* __restrict__ B3, float* __restrict__ Cout)
{
  __shared__ __align__(16) uint16_t sA[128 * 64];
  __shared__ __align__(16) uint16_t sB[128 * 64];
  const int tid  = threadIdx.x;
  const int lane = tid & 63;
  const int wave = tid >> 6;
  const int arow0 = blockIdx.x * 128;
  const int bcol0 = blockIdx.y * 128;
  const int wr = (wave >> 1) * 64;
  const int wc = (wave & 1) * 64;

  const f32x4 fzero = {0.f, 0.f, 0.f, 0.f};
  f32x4 acc[4][4];
#pragma unroll
  for (int i = 0; i < 4; ++i)
#pragma unroll
    for (int j = 0; j < 4; ++j)
      acc[i][j] = fzero;

  size_t aOff[4], bOff[4];
  int ldsOff[4];
#pragma unroll
  for (int i = 0; i < 4; ++i){
    int o = i * 256 + tid;
    int row = o >> 3;
    int ss = (o & 7) ^ (row & 7);
    aOff[i] = (size_t)(arow0 + row) * CDIM + ss * 8;
    bOff[i] = (size_t)(bcol0 + row) * K3 + ss * 8;
    ldsOff[i] = (i * 256 + wave * 64) * 16;
  }

  int aRd[2][4], bRd[2][4];
#pragma unroll
  for (int ks = 0; ks < 2; ++ks){
    int sw = ((lane >> 4) + ks * 4) ^ (lane & 7);
#pragma unroll
    for (int mi = 0; mi < 4; ++mi){
      aRd[ks][mi] = (wr + mi * 16 + (lane & 15)) * 128 + sw * 16;
      bRd[ks][mi] = (wc + mi * 16 + (lane & 15)) * 128 + sw * 16;
    }
  }

  const char* sAc = (const char*)sA;
  const char* sBc = (const char*)sB;

  for (int step = 0; step < K3 / 64; ++step){
    const int kv0 = step * 64;
    const uint16_t* Abase = ((kv0 >> 10) == 1) ? Alo : Ahi;
    const int kr0 = kv0 & 1023;
#pragma unroll
    for (int i = 0; i < 4; ++i){
      async16(Abase + aOff[i] + kr0, (char*)sA + ldsOff[i]);
      async16(B3    + bOff[i] + kv0, (char*)sB + ldsOff[i]);
    }
    __syncthreads();
#pragma unroll
    for (int ks = 0; ks < 2; ++ks){
      bf16x8 af[4], bfr[4];
#pragma unroll
      for (int mi = 0; mi < 4; ++mi) af[mi]  = *(const bf16x8*)(sAc + aRd[ks][mi]);
#pragma unroll
      for (int ni = 0; ni < 4; ++ni) bfr[ni] = *(const bf16x8*)(sBc + bRd[ks][ni]);
#pragma unroll
      for (int mi = 0; mi < 4; ++mi)
#pragma unroll
        for (int ni = 0; ni < 4; ++ni)
          acc[mi][ni] = __builtin_amdgcn_mfma_f32_16x16x32_bf16(af[mi], bfr[ni], acc[mi][ni], 0, 0, 0);
    }
    __syncthreads();
  }

#pragma unroll
  for (int mi = 0; mi < 4; ++mi){
    const int row = arow0 + wr + mi * 16 + (lane >> 4) * 4;
#pragma unroll
    for (int r = 0; r < 4; ++r){
      float* crow = Cout + (size_t)(row + r) * CDIM + bcol0 + wc + (lane & 15);
#pragma unroll
      for (int ni = 0; ni < 4; ++ni)
        crow[ni * 16] = acc[mi][ni][r];
    }
  }
}

// ---------------- 256x256 8-phase GEMM template (T3+T4+T5 + nt-stores) ----------------
// NSTEP: virtual-K tiles (48 = x3, 16 = x1); BSTR: B row stride; X3: A phase switching.
// grid (4, Mt) x-fastest: XCD = id%8 -> each XCD keeps one B column-panel L2-resident;
// C stored non-temporally so streaming writes don't evict the shared A window from L2/L3.
template<int NSTEP, int BSTR, bool X3>
__global__ __launch_bounds__(512, 1)
void gemm8_t(const uint16_t* __restrict__ Ahi, const uint16_t* __restrict__ Alo,
             const uint16_t* __restrict__ B3, float* __restrict__ Cout)
{
  __shared__ __align__(16) char smem[131072];   // A: [0,64K), B: [64K,128K); 32K per buf
  const int tid  = threadIdx.x;
  const int lane = tid & 63;
  const int wave = tid >> 6;        // 0..7
  const int wave_m = wave >> 2;     // 0..1 -> 128 rows each
  const int wave_n = wave & 3;      // 0..3 -> 64 cols each
  const int arow0 = blockIdx.y * 256;
  const int bcol0 = blockIdx.x * 256;

  const f32x4 fzero = {0.f, 0.f, 0.f, 0.f};
  f32x4 acc[8][4];
#pragma unroll
  for (int i = 0; i < 8; ++i)
#pragma unroll
    for (int j = 0; j < 4; ++j)
      acc[i][j] = fzero;

  const int abase0 = (wave_m * 128 + (lane & 15)) * 128;
  const int bbase0 = (wave_n * 64  + (lane & 15)) * 128;
  const int s0 = (((lane >> 4))     ^ (lane & 7)) * 16;
  const int s1 = ((4 + (lane >> 4)) ^ (lane & 7)) * 16;

  size_t aU[2][2], bU[2][2];
  int ldsU[2][2];
#pragma unroll
  for (int h = 0; h < 2; ++h)
#pragma unroll
    for (int j = 0; j < 2; ++j){
      int u = h * 1024 + (wave * 2 + j) * 64 + lane;
      int row = u >> 3;
      int ss = (u & 7) ^ (row & 7);          // pre-swizzled source slot (rule #21)
      aU[h][j] = (size_t)(arow0 + row) * CDIM + ss * 8;
      bU[h][j] = (size_t)(bcol0 + row) * BSTR + ss * 8;
      ldsU[h][j] = (h * 1024 + (wave * 2 + j) * 64) * 16;
    }

  auto stA = [&](int h, int tt, int dsel){
    const uint16_t* base = (X3 && ((tt >> 4) == 1)) ? Alo : Ahi;  // x3 phases: hi,lo,hi
    const int kr0 = X3 ? ((tt * 64) & 1023) : (tt * 64);
    async16(base + aU[h][0] + kr0, smem + dsel + ldsU[h][0]);
    async16(base + aU[h][1] + kr0, smem + dsel + ldsU[h][1]);
  };
  auto stB = [&](int h, int tt, int dsel){
    const int k0 = tt * 64;
    async16(B3 + bU[h][0] + k0, smem + 65536 + dsel + ldsU[h][0]);
    async16(B3 + bU[h][1] + k0, smem + 65536 + dsel + ldsU[h][1]);
  };

#define RDA(dst, M, As) { dst[0] = *(const bf16x8*)((As) + abase0 + (M)*2048 + s0); \
                          dst[1] = *(const bf16x8*)((As) + abase0 + (M)*2048 + s1); }
#define MM(MI, AF) { _Pragma("unroll") for (int n = 0; n < 4; ++n){ \
    acc[MI][n] = __builtin_amdgcn_mfma_f32_16x16x32_bf16(AF[0], bf[n][0], acc[MI][n], 0, 0, 0); \
    acc[MI][n] = __builtin_amdgcn_mfma_f32_16x16x32_bf16(AF[1], bf[n][1], acc[MI][n], 0, 0, 0); } }

  // prologue: tile0 {B0,B1,A0,A1} -> buf0; tile1 {B0,B1,A0} -> buf1  (A1[1] lands in t=0 ph0)
  stB(0, 0, 0);     stB(1, 0, 0);     stA(0, 0, 0);     stA(1, 0, 0);
  stB(0, 1, 32768); stB(1, 1, 32768); stA(0, 1, 32768);
  asm volatile("s_waitcnt vmcnt(6)" ::: "memory");
  __builtin_amdgcn_sched_barrier(0);
  __builtin_amdgcn_s_barrier();

#pragma unroll 2
  for (int t = 0; t < NSTEP; ++t){
    const int sel  = (t & 1) * 32768;
    const int seln = 32768 - sel;
    const char* As = smem + sel;
    const char* Bs = smem + 65536 + sel;

    bf16x8 bf[4][2], a0[2], a1[2], a2[2], a3[2], a4[2], a5[2], a6[2], a7[2];

    // phase 0: read all B + A m0,m1; stage A1[t+1] -> other buf
#pragma unroll
    for (int n = 0; n < 4; ++n){
      bf[n][0] = *(const bf16x8*)(Bs + bbase0 + n * 2048 + s0);
      bf[n][1] = *(const bf16x8*)(Bs + bbase0 + n * 2048 + s1);
    }
    RDA(a0, 0, As); RDA(a1, 1, As);
    if (t + 1 < NSTEP) stA(1, t + 1, seln);
    __builtin_amdgcn_s_barrier();
    __builtin_amdgcn_s_setprio(1);
    MM(0, a0); MM(1, a1);
    __builtin_amdgcn_s_setprio(0);
    __builtin_amdgcn_s_barrier();

    // phase 1: read A m2..m5; stage B0[t+2]
    RDA(a2, 2, As); RDA(a3, 3, As); RDA(a4, 4, As); RDA(a5, 5, As);
    if (t + 2 < NSTEP) stB(0, t + 2, sel);
    __builtin_amdgcn_s_barrier();
    __builtin_amdgcn_s_setprio(1);
    MM(2, a2); MM(3, a3);
    __builtin_amdgcn_s_setprio(0);
    __builtin_amdgcn_s_barrier();

    // phase 2: read A m6,m7; stage B1[t+2]
    RDA(a6, 6, As); RDA(a7, 7, As);
    if (t + 2 < NSTEP) stB(1, t + 2, sel);
    __builtin_amdgcn_s_barrier();
    __builtin_amdgcn_s_setprio(1);
    MM(4, a4); MM(5, a5);
    __builtin_amdgcn_s_setprio(0);
    asm volatile("s_waitcnt lgkmcnt(0)" ::: "memory");  // a6,a7 in-register before A0 restage
    __builtin_amdgcn_sched_barrier(0);
    __builtin_amdgcn_s_barrier();

    // phase 3: stage A0[t+2]; counted vmcnt at K-tile boundary
    if (t + 2 < NSTEP) stA(0, t + 2, sel);
    if (t <= NSTEP - 3) { asm volatile("s_waitcnt vmcnt(6)" ::: "memory"); }
    else                { asm volatile("s_waitcnt vmcnt(0)" ::: "memory"); }
    __builtin_amdgcn_sched_barrier(0);
    __builtin_amdgcn_s_barrier();
    __builtin_amdgcn_s_setprio(1);
    MM(6, a6); MM(7, a7);
    __builtin_amdgcn_s_setprio(0);
    __builtin_amdgcn_s_barrier();
  }
#undef RDA
#undef MM

#pragma unroll
  for (int mi = 0; mi < 8; ++mi){
    const int row = arow0 + wave_m * 128 + mi * 16 + (lane >> 4) * 4;
#pragma unroll
    for (int r = 0; r < 4; ++r){
      float* crow = Cout + (size_t)(row + r) * CDIM + bcol0 + wave_n * 64 + (lane & 15);
#pragma unroll
      for (int ni = 0; ni < 4; ++ni)
        __builtin_nontemporal_store(acc[mi][ni][r], &crow[ni * 16]);
    }
  }
}

// ---------------- fused RoPE + attention (l = 12 query only) ----------------
__global__ void attn_kernel(const float* __restrict__ Kb, const float* __restrict__ Vb,
                            const float* __restrict__ q, const float* __restrict__ cosT,
                            const float* __restrict__ sinT, uint16_t* __restrict__ ohi,
                            uint16_t* __restrict__ olo, int n0)
{
  int wid  = blockIdx.x * 4 + (threadIdx.x >> 6);
  int lane = threadIdx.x & 63;
  int nl = wid >> 4;
  int h  = wid & 15;
  int d = lane, i = d & 31;

  size_t qoff = (size_t)(n0 + nl) * CDIM + h * 64 + d;
  float qv = q[qoff];
  float qp = __shfl_xor(qv, 32);
  float cq = cosT[12 * 32 + i], sq = sinT[12 * 32 + i];
  float qr = (d < 32) ? (qv * cq - qp * sq) : (qv * cq + qp * sq);

  const float* Kp = Kb + (size_t)nl * (LSEQ * CDIM) + h * 64 + d;
  const float* Vp = Vb + (size_t)nl * (LSEQ * CDIM) + h * 64 + d;

  float s[LSEQ];
#pragma unroll
  for (int m = 0; m < LSEQ; ++m){
    float kv = Kp[m * CDIM];
    float kp = __shfl_xor(kv, 32);
    float cm = cosT[m * 32 + i], sm = sinT[m * 32 + i];
    float kr = (d < 32) ? (kv * cm - kp * sm) : (kv * cm + kp * sm);
    float p = qr * kr;
    p += __shfl_xor(p, 32); p += __shfl_xor(p, 16); p += __shfl_xor(p, 8);
    p += __shfl_xor(p, 4);  p += __shfl_xor(p, 2);  p += __shfl_xor(p, 1);
    s[m] = p * 0.125f;
  }
  float mx = s[0];
#pragma unroll
  for (int m = 1; m < LSEQ; ++m) mx = fmaxf(mx, s[m]);
  float sum = 0.f;
#pragma unroll
  for (int m = 0; m < LSEQ; ++m){ s[m] = expf(s[m] - mx); sum += s[m]; }
  float inv = 1.0f / sum;
  float o = 0.f;
#pragma unroll
  for (int m = 0; m < LSEQ; ++m) o += s[m] * Vp[m * CDIM];
  o *= inv;
  uint16_t hb = f2bf(o);
  uint16_t lb = f2bf(o - bf2f(hb));
  ohi[qoff] = hb;
  olo[qoff] = lb;
}

// ---------------- host ----------------
extern "C" void kernel_launch(void* const* d_in, const int* in_sizes, int n_in,
                              void* d_out, int out_size, void* d_ws, size_t ws_size,
                              hipStream_t stream)
{
  (void)in_sizes; (void)n_in; (void)out_size;
  const float* src = (const float*)d_in[0];
  const float* Wq  = (const float*)d_in[1];
  const float* Wk  = (const float*)d_in[2];
  const float* Wv  = (const float*)d_in[3];
  const float* Wo  = (const float*)d_in[4];
  float* out = (float*)d_out;

  // adaptive chunk (cn multiple of 256 so cn*13 divides by 256-row tiles)
  int cn = 4096;
  while (cn > 256 && (77700000ull + (size_t)cn * 159744ull) > ws_size) cn >>= 1;
  const int nchunks = NTOK / cn;

  char* p = (char*)d_ws;
  auto carve = [&](size_t bytes) -> void* {
    void* r = (void*)p; p += (bytes + 255) & ~(size_t)255; return r;
  };
  uint16_t* W3q = (uint16_t*)carve((size_t)CDIM * K3 * 2);
  uint16_t* W3k = (uint16_t*)carve((size_t)CDIM * K3 * 2);
  uint16_t* W1v = (uint16_t*)carve((size_t)CDIM * CDIM * 2);
  uint16_t* W3o = (uint16_t*)carve((size_t)CDIM * K3 * 2);
  float* cosT = (float*)carve(LSEQ * 32 * 4);
  float* sinT = (float*)carve(LSEQ * 32 * 4);
  uint16_t* Aqh = (uint16_t*)carve((size_t)NTOK * CDIM * 2);
  uint16_t* Aql = (uint16_t*)carve((size_t)NTOK * CDIM * 2);
  float* qbuf   = (float*)carve((size_t)NTOK * CDIM * 4);
  uint16_t* ohi = (uint16_t*)carve((size_t)NTOK * CDIM * 2);
  uint16_t* olo = (uint16_t*)carve((size_t)NTOK * CDIM * 2);
  uint16_t* Ah  = (uint16_t*)carve((size_t)cn * LSEQ * CDIM * 2);
  uint16_t* Al  = (uint16_t*)carve((size_t)cn * LSEQ * CDIM * 2);
  float* Kb     = (float*)carve((size_t)cn * LSEQ * CDIM * 4);
  float* Vb     = (float*)carve((size_t)cn * LSEQ * CDIM * 4);

  convert_W<<<1024, 256, 0, stream>>>(Wq, W3q);
  convert_W<<<1024, 256, 0, stream>>>(Wk, W3k);
  convert_W1<<<1024, 256, 0, stream>>>(Wv, W1v);
  convert_W<<<1024, 256, 0, stream>>>(Wo, W3o);
  rope_table<<<1, 512, 0, stream>>>(cosT, sinT);
  convert_Aq<<<NTOK, 256, 0, stream>>>(src, Aqh, Aql);
  gemm_x3<<<dim3(NTOK / 128, 8), 256, 0, stream>>>(Aqh, Aql, W3q, qbuf);

  for (int c = 0; c < nchunks; ++c){
    const int mt = cn * LSEQ / 256;       // 256-row tiles
    convert_A<<<cn * LSEQ, 256, 0, stream>>>(src, Ah, Al, c * cn);
    gemm8_t<48, K3,   true ><<<dim3(4, mt), 512, 0, stream>>>(Ah, Al, W3k, Kb);
    gemm8_t<16, CDIM, false><<<dim3(4, mt), 512, 0, stream>>>(Ah, Al, W1v, Vb);
    attn_kernel<<<cn * 4, 256, 0, stream>>>(Kb, Vb, qbuf, cosT, sinT, ohi, olo, c * cn);
  }
  gemm_x3<<<dim3(NTOK / 128, 8), 256, 0, stream>>>(ohi, olo, W3o, out);
}

// Round 7
// 759.980 us; speedup vs baseline: 1.2957x; 1.0499x over previous
//
#include <hip/hip_runtime.h>
#include <stdint.h>

typedef __attribute__((ext_vector_type(4))) float f32x4;
typedef __attribute__((ext_vector_type(8))) __bf16 bf16x8;
typedef __attribute__((ext_vector_type(4))) uint16_t u16x4;

#define CDIM 1024
#define K3   3072
#define LSEQ 13
#define NTOK 4096

__device__ __forceinline__ uint16_t f2bf(float x){
  union { float f; uint32_t u; } c; c.f = x;
  uint32_t r = (c.u + 0x7FFFu + ((c.u >> 16) & 1u)) >> 16;
  return (uint16_t)r;
}
__device__ __forceinline__ float bf2f(uint16_t h){
  union { uint32_t u; float f; } c; c.u = ((uint32_t)h) << 16;
  return c.f;
}

__device__ __forceinline__ void async16(const void* g, void* l){
  __builtin_amdgcn_global_load_lds((__attribute__((address_space(1))) void*)(g),
                                   (__attribute__((address_space(3))) void*)(l), 16, 0, 0);
}

// ---------------- conversion kernels ----------------

// W fp32 -> [1024][3072] bf16 = [hi | hi | lo]   (x3 virtual-K layout)
__global__ void convert_W(const float* __restrict__ W, uint16_t* __restrict__ W3){
  int idx = blockIdx.x * 256 + threadIdx.x;
  int j = idx >> 8;
  int c4 = (idx & 255) * 4;
  float4 v = *(const float4*)(W + (size_t)j * CDIM + c4);
  u16x4 h, lo;
  h.x = f2bf(v.x); lo.x = f2bf(v.x - bf2f(h.x));
  h.y = f2bf(v.y); lo.y = f2bf(v.y - bf2f(h.y));
  h.z = f2bf(v.z); lo.z = f2bf(v.z - bf2f(h.z));
  h.w = f2bf(v.w); lo.w = f2bf(v.w - bf2f(h.w));
  uint16_t* r = W3 + (size_t)j * K3;
  *(u16x4*)(r + c4)        = h;
  *(u16x4*)(r + 1024 + c4) = h;
  *(u16x4*)(r + 2048 + c4) = lo;
}

// W fp32 -> [1024][1024] bf16 hi only   (x1 layout, V projection)
__global__ void convert_W1(const float* __restrict__ W, uint16_t* __restrict__ W1){
  int idx = blockIdx.x * 256 + threadIdx.x;
  int j = idx >> 8;
  int c4 = (idx & 255) * 4;
  float4 v = *(const float4*)(W + (size_t)j * CDIM + c4);
  u16x4 h;
  h.x = f2bf(v.x); h.y = f2bf(v.y); h.z = f2bf(v.z); h.w = f2bf(v.w);
  *(u16x4*)(W1 + (size_t)j * CDIM + c4) = h;
}

__global__ void rope_table(float* __restrict__ cosT, float* __restrict__ sinT){
  int t = threadIdx.x;
  if (t < LSEQ * 32){
    int l = t >> 5, i = t & 31;
    float inv = 1.0f / powf(10000.0f, ((float)(2 * i)) / 64.0f);
    float a = (float)l * inv;
    cosT[t] = cosf(a);
    sinT[t] = sinf(a);
  }
}

__global__ void convert_A(const float* __restrict__ src, uint16_t* __restrict__ Ah,
                          uint16_t* __restrict__ Al, int n0){
  int idx = blockIdx.x * 256 + threadIdx.x;
  int row = idx >> 8;
  int c4 = (idx & 255) * 4;
  int nl = row / 13;
  int l  = row - nl * 13;
  float4 v = *(const float4*)(src + (size_t)l * (NTOK * CDIM) + (size_t)(n0 + nl) * CDIM + c4);
  u16x4 h, lo;
  h.x = f2bf(v.x); lo.x = f2bf(v.x - bf2f(h.x));
  h.y = f2bf(v.y); lo.y = f2bf(v.y - bf2f(h.y));
  h.z = f2bf(v.z); lo.z = f2bf(v.z - bf2f(h.z));
  h.w = f2bf(v.w); lo.w = f2bf(v.w - bf2f(h.w));
  *(u16x4*)(Ah + (size_t)row * CDIM + c4) = h;
  *(u16x4*)(Al + (size_t)row * CDIM + c4) = lo;
}

__global__ void convert_Aq(const float* __restrict__ src, uint16_t* __restrict__ Ah,
                           uint16_t* __restrict__ Al){
  int idx = blockIdx.x * 256 + threadIdx.x;
  int n = idx >> 8;
  int c4 = (idx & 255) * 4;
  float4 v = *(const float4*)(src + (size_t)12 * (NTOK * CDIM) + (size_t)n * CDIM + c4);
  u16x4 h, lo;
  h.x = f2bf(v.x); lo.x = f2bf(v.x - bf2f(h.x));
  h.y = f2bf(v.y); lo.y = f2bf(v.y - bf2f(h.y));
  h.z = f2bf(v.z); lo.z = f2bf(v.z - bf2f(h.z));
  h.w = f2bf(v.w); lo.w = f2bf(v.w - bf2f(h.w));
  *(u16x4*)(Ah + (size_t)n * CDIM + c4) = h;
  *(u16x4*)(Al + (size_t)n * CDIM + c4) = lo;
}

// ---------------- 128x128 bf16x3 GEMM (2-barrier structure) — Q and O projections ----------------
__global__ __launch_bounds__(256, 2)
void gemm_x3(const uint16_t* __restrict__ Ahi, const uint16_t* __restrict__ Alo,
             const uint16_t* __restrict__ B3, float* __restrict__ Cout)
{
  __shared__ __align__(16) uint16_t sA[128 * 64];
  __shared__ __align__(16) uint16_t sB[128 * 64];
  const int tid  = threadIdx.x;
  const int lane = tid & 63;
  const int wave = tid >> 6;
  const int arow0 = blockIdx.x * 128;
  const int bcol0 = blockIdx.y * 128;
  const int wr = (wave >> 1) * 64;
  const int wc = (wave & 1) * 64;

  const f32x4 fzero = {0.f, 0.f, 0.f, 0.f};
  f32x4 acc[4][4];
#pragma unroll
  for (int i = 0; i < 4; ++i)
#pragma unroll
    for (int j = 0; j < 4; ++j)
      acc[i][j] = fzero;

  size_t aOff[4], bOff[4];
  int ldsOff[4];
#pragma unroll
  for (int i = 0; i < 4; ++i){
    int o = i * 256 + tid;
    int row = o >> 3;
    int ss = (o & 7) ^ (row & 7);
    aOff[i] = (size_t)(arow0 + row) * CDIM + ss * 8;
    bOff[i] = (size_t)(bcol0 + row) * K3 + ss * 8;
    ldsOff[i] = (i * 256 + wave * 64) * 16;
  }

  int aRd[2][4], bRd[2][4];
#pragma unroll
  for (int ks = 0; ks < 2; ++ks){
    int sw = ((lane >> 4) + ks * 4) ^ (lane & 7);
#pragma unroll
    for (int mi = 0; mi < 4; ++mi){
      aRd[ks][mi] = (wr + mi * 16 + (lane & 15)) * 128 + sw * 16;
      bRd[ks][mi] = (wc + mi * 16 + (lane & 15)) * 128 + sw * 16;
    }
  }

  const char* sAc = (const char*)sA;
  const char* sBc = (const char*)sB;

  for (int step = 0; step < K3 / 64; ++step){
    const int kv0 = step * 64;
    const uint16_t* Abase = ((kv0 >> 10) == 1) ? Alo : Ahi;
    const int kr0 = kv0 & 1023;
#pragma unroll
    for (int i = 0; i < 4; ++i){
      async16(Abase + aOff[i] + kr0, (char*)sA + ldsOff[i]);
      async16(B3    + bOff[i] + kv0, (char*)sB + ldsOff[i]);
    }
    __syncthreads();
#pragma unroll
    for (int ks = 0; ks < 2; ++ks){
      bf16x8 af[4], bfr[4];
#pragma unroll
      for (int mi = 0; mi < 4; ++mi) af[mi]  = *(const bf16x8*)(sAc + aRd[ks][mi]);
#pragma unroll
      for (int ni = 0; ni < 4; ++ni) bfr[ni] = *(const bf16x8*)(sBc + bRd[ks][ni]);
#pragma unroll
      for (int mi = 0; mi < 4; ++mi)
#pragma unroll
        for (int ni = 0; ni < 4; ++ni)
          acc[mi][ni] = __builtin_amdgcn_mfma_f32_16x16x32_bf16(af[mi], bfr[ni], acc[mi][ni], 0, 0, 0);
    }
    __syncthreads();
  }

#pragma unroll
  for (int mi = 0; mi < 4; ++mi){
    const int row = arow0 + wr + mi * 16 + (lane >> 4) * 4;
#pragma unroll
    for (int r = 0; r < 4; ++r){
      float* crow = Cout + (size_t)(row + r) * CDIM + bcol0 + wc + (lane & 15);
#pragma unroll
      for (int ni = 0; ni < 4; ++ni)
        crow[ni * 16] = acc[mi][ni][r];
    }
  }
}

// ---------------- 256x256 8-phase GEMM template (T3+T4+T5) ----------------
// NSTEP: virtual-K tiles (48 = x3, 16 = x1); BSTR: B row stride; X3: A phase switch;
// OUTBF16: store C as bf16 (V path) vs fp32 (K path). Plain stores (nt regressed, R6).
template<int NSTEP, int BSTR, bool X3, bool OUTBF16>
__global__ __launch_bounds__(512, 1)
void gemm8_t(const uint16_t* __restrict__ Ahi, const uint16_t* __restrict__ Alo,
             const uint16_t* __restrict__ B3, void* __restrict__ CoutV)
{
  __shared__ __align__(16) char smem[131072];   // A: [0,64K), B: [64K,128K); 32K per buf
  const int tid  = threadIdx.x;
  const int lane = tid & 63;
  const int wave = tid >> 6;        // 0..7
  const int wave_m = wave >> 2;     // 0..1 -> 128 rows each
  const int wave_n = wave & 3;      // 0..3 -> 64 cols each
  const int arow0 = blockIdx.y * 256;
  const int bcol0 = blockIdx.x * 256;

  const f32x4 fzero = {0.f, 0.f, 0.f, 0.f};
  f32x4 acc[8][4];
#pragma unroll
  for (int i = 0; i < 8; ++i)
#pragma unroll
    for (int j = 0; j < 4; ++j)
      acc[i][j] = fzero;

  const int abase0 = (wave_m * 128 + (lane & 15)) * 128;
  const int bbase0 = (wave_n * 64  + (lane & 15)) * 128;
  const int s0 = (((lane >> 4))     ^ (lane & 7)) * 16;
  const int s1 = ((4 + (lane >> 4)) ^ (lane & 7)) * 16;

  size_t aU[2][2], bU[2][2];
  int ldsU[2][2];
#pragma unroll
  for (int h = 0; h < 2; ++h)
#pragma unroll
    for (int j = 0; j < 2; ++j){
      int u = h * 1024 + (wave * 2 + j) * 64 + lane;
      int row = u >> 3;
      int ss = (u & 7) ^ (row & 7);          // pre-swizzled source slot (rule #21)
      aU[h][j] = (size_t)(arow0 + row) * CDIM + ss * 8;
      bU[h][j] = (size_t)(bcol0 + row) * BSTR + ss * 8;
      ldsU[h][j] = (h * 1024 + (wave * 2 + j) * 64) * 16;
    }

  auto stA = [&](int h, int tt, int dsel){
    const uint16_t* base = (X3 && ((tt >> 4) == 1)) ? Alo : Ahi;  // x3 phases: hi,lo,hi
    const int kr0 = X3 ? ((tt * 64) & 1023) : (tt * 64);
    async16(base + aU[h][0] + kr0, smem + dsel + ldsU[h][0]);
    async16(base + aU[h][1] + kr0, smem + dsel + ldsU[h][1]);
  };
  auto stB = [&](int h, int tt, int dsel){
    const int k0 = tt * 64;
    async16(B3 + bU[h][0] + k0, smem + 65536 + dsel + ldsU[h][0]);
    async16(B3 + bU[h][1] + k0, smem + 65536 + dsel + ldsU[h][1]);
  };

#define RDA(dst, M, As) { dst[0] = *(const bf16x8*)((As) + abase0 + (M)*2048 + s0); \
                          dst[1] = *(const bf16x8*)((As) + abase0 + (M)*2048 + s1); }
#define MM(MI, AF) { _Pragma("unroll") for (int n = 0; n < 4; ++n){ \
    acc[MI][n] = __builtin_amdgcn_mfma_f32_16x16x32_bf16(AF[0], bf[n][0], acc[MI][n], 0, 0, 0); \
    acc[MI][n] = __builtin_amdgcn_mfma_f32_16x16x32_bf16(AF[1], bf[n][1], acc[MI][n], 0, 0, 0); } }

  // prologue: tile0 {B0,B1,A0,A1} -> buf0; tile1 {B0,B1,A0} -> buf1  (A1[1] lands in t=0 ph0)
  stB(0, 0, 0);     stB(1, 0, 0);     stA(0, 0, 0);     stA(1, 0, 0);
  stB(0, 1, 32768); stB(1, 1, 32768); stA(0, 1, 32768);
  asm volatile("s_waitcnt vmcnt(6)" ::: "memory");
  __builtin_amdgcn_sched_barrier(0);
  __builtin_amdgcn_s_barrier();

#pragma unroll 2
  for (int t = 0; t < NSTEP; ++t){
    const int sel  = (t & 1) * 32768;
    const int seln = 32768 - sel;
    const char* As = smem + sel;
    const char* Bs = smem + 65536 + sel;

    bf16x8 bf[4][2], a0[2], a1[2], a2[2], a3[2], a4[2], a5[2], a6[2], a7[2];

    // phase 0: read all B + A m0,m1; stage A1[t+1] -> other buf
#pragma unroll
    for (int n = 0; n < 4; ++n){
      bf[n][0] = *(const bf16x8*)(Bs + bbase0 + n * 2048 + s0);
      bf[n][1] = *(const bf16x8*)(Bs + bbase0 + n * 2048 + s1);
    }
    RDA(a0, 0, As); RDA(a1, 1, As);
    if (t + 1 < NSTEP) stA(1, t + 1, seln);
    __builtin_amdgcn_s_barrier();
    __builtin_amdgcn_s_setprio(1);
    MM(0, a0); MM(1, a1);
    __builtin_amdgcn_s_setprio(0);
    __builtin_amdgcn_s_barrier();

    // phase 1: read A m2..m5; stage B0[t+2]
    RDA(a2, 2, As); RDA(a3, 3, As); RDA(a4, 4, As); RDA(a5, 5, As);
    if (t + 2 < NSTEP) stB(0, t + 2, sel);
    __builtin_amdgcn_s_barrier();
    __builtin_amdgcn_s_setprio(1);
    MM(2, a2); MM(3, a3);
    __builtin_amdgcn_s_setprio(0);
    __builtin_amdgcn_s_barrier();

    // phase 2: read A m6,m7; stage B1[t+2]
    RDA(a6, 6, As); RDA(a7, 7, As);
    if (t + 2 < NSTEP) stB(1, t + 2, sel);
    __builtin_amdgcn_s_barrier();
    __builtin_amdgcn_s_setprio(1);
    MM(4, a4); MM(5, a5);
    __builtin_amdgcn_s_setprio(0);
    asm volatile("s_waitcnt lgkmcnt(0)" ::: "memory");  // a6,a7 in-register before A0 restage
    __builtin_amdgcn_sched_barrier(0);
    __builtin_amdgcn_s_barrier();

    // phase 3: stage A0[t+2]; counted vmcnt at K-tile boundary
    if (t + 2 < NSTEP) stA(0, t + 2, sel);
    if (t <= NSTEP - 3) { asm volatile("s_waitcnt vmcnt(6)" ::: "memory"); }
    else                { asm volatile("s_waitcnt vmcnt(0)" ::: "memory"); }
    __builtin_amdgcn_sched_barrier(0);
    __builtin_amdgcn_s_barrier();
    __builtin_amdgcn_s_setprio(1);
    MM(6, a6); MM(7, a7);
    __builtin_amdgcn_s_setprio(0);
    __builtin_amdgcn_s_barrier();
  }
#undef RDA
#undef MM

#pragma unroll
  for (int mi = 0; mi < 8; ++mi){
    const int row = arow0 + wave_m * 128 + mi * 16 + (lane >> 4) * 4;
#pragma unroll
    for (int r = 0; r < 4; ++r){
      const size_t co = (size_t)(row + r) * CDIM + bcol0 + wave_n * 64 + (lane & 15);
      if constexpr (OUTBF16){
        uint16_t* crow = (uint16_t*)CoutV + co;
#pragma unroll
        for (int ni = 0; ni < 4; ++ni)
          crow[ni * 16] = f2bf(acc[mi][ni][r]);
      } else {
        float* crow = (float*)CoutV + co;
#pragma unroll
        for (int ni = 0; ni < 4; ++ni)
          crow[ni * 16] = acc[mi][ni][r];
      }
    }
  }
}

// ---------------- fused RoPE + attention (l = 12 query only) ----------------
__global__ void attn_kernel(const float* __restrict__ Kb, const uint16_t* __restrict__ Vb,
                            const float* __restrict__ q, const float* __restrict__ cosT,
                            const float* __restrict__ sinT, uint16_t* __restrict__ ohi,
                            uint16_t* __restrict__ olo, int n0)
{
  int wid  = blockIdx.x * 4 + (threadIdx.x >> 6);
  int lane = threadIdx.x & 63;
  int nl = wid >> 4;
  int h  = wid & 15;
  int d = lane, i = d & 31;

  size_t qoff = (size_t)(n0 + nl) * CDIM + h * 64 + d;
  float qv = q[qoff];
  float qp = __shfl_xor(qv, 32);
  float cq = cosT[12 * 32 + i], sq = sinT[12 * 32 + i];
  float qr = (d < 32) ? (qv * cq - qp * sq) : (qv * cq + qp * sq);

  const float*    Kp = Kb + (size_t)nl * (LSEQ * CDIM) + h * 64 + d;
  const uint16_t* Vp = Vb + (size_t)nl * (LSEQ * CDIM) + h * 64 + d;

  float s[LSEQ];
#pragma unroll
  for (int m = 0; m < LSEQ; ++m){
    float kv = Kp[m * CDIM];
    float kp = __shfl_xor(kv, 32);
    float cm = cosT[m * 32 + i], sm = sinT[m * 32 + i];
    float kr = (d < 32) ? (kv * cm - kp * sm) : (kv * cm + kp * sm);
    float p = qr * kr;
    p += __shfl_xor(p, 32); p += __shfl_xor(p, 16); p += __shfl_xor(p, 8);
    p += __shfl_xor(p, 4);  p += __shfl_xor(p, 2);  p += __shfl_xor(p, 1);
    s[m] = p * 0.125f;
  }
  float mx = s[0];
#pragma unroll
  for (int m = 1; m < LSEQ; ++m) mx = fmaxf(mx, s[m]);
  float sum = 0.f;
#pragma unroll
  for (int m = 0; m < LSEQ; ++m){ s[m] = expf(s[m] - mx); sum += s[m]; }
  float inv = 1.0f / sum;
  float o = 0.f;
#pragma unroll
  for (int m = 0; m < LSEQ; ++m) o += s[m] * bf2f(Vp[m * CDIM]);
  o *= inv;
  uint16_t hb = f2bf(o);
  uint16_t lb = f2bf(o - bf2f(hb));
  ohi[qoff] = hb;
  olo[qoff] = lb;
}

// ---------------- host ----------------
extern "C" void kernel_launch(void* const* d_in, const int* in_sizes, int n_in,
                              void* d_out, int out_size, void* d_ws, size_t ws_size,
                              hipStream_t stream)
{
  (void)in_sizes; (void)n_in; (void)out_size;
  const float* src = (const float*)d_in[0];
  const float* Wq  = (const float*)d_in[1];
  const float* Wk  = (const float*)d_in[2];
  const float* Wv  = (const float*)d_in[3];
  const float* Wo  = (const float*)d_in[4];
  float* out = (float*)d_out;

  // adaptive chunk (cn multiple of 256 so cn*13 divides by 256-row tiles)
  int cn = 4096;
  while (cn > 256 && (77700000ull + (size_t)cn * 133120ull) > ws_size) cn >>= 1;
  const int nchunks = NTOK / cn;

  char* p = (char*)d_ws;
  auto carve = [&](size_t bytes) -> void* {
    void* r = (void*)p; p += (bytes + 255) & ~(size_t)255; return r;
  };
  uint16_t* W3q = (uint16_t*)carve((size_t)CDIM * K3 * 2);
  uint16_t* W3k = (uint16_t*)carve((size_t)CDIM * K3 * 2);
  uint16_t* W1v = (uint16_t*)carve((size_t)CDIM * CDIM * 2);
  uint16_t* W3o = (uint16_t*)carve((size_t)CDIM * K3 * 2);
  float* cosT = (float*)carve(LSEQ * 32 * 4);
  float* sinT = (float*)carve(LSEQ * 32 * 4);
  uint16_t* Aqh = (uint16_t*)carve((size_t)NTOK * CDIM * 2);
  uint16_t* Aql = (uint16_t*)carve((size_t)NTOK * CDIM * 2);
  float* qbuf   = (float*)carve((size_t)NTOK * CDIM * 4);
  uint16_t* ohi = (uint16_t*)carve((size_t)NTOK * CDIM * 2);
  uint16_t* olo = (uint16_t*)carve((size_t)NTOK * CDIM * 2);
  uint16_t* Ah  = (uint16_t*)carve((size_t)cn * LSEQ * CDIM * 2);
  uint16_t* Al  = (uint16_t*)carve((size_t)cn * LSEQ * CDIM * 2);
  float* Kb     = (float*)carve((size_t)cn * LSEQ * CDIM * 4);
  uint16_t* Vb  = (uint16_t*)carve((size_t)cn * LSEQ * CDIM * 2);

  convert_W<<<1024, 256, 0, stream>>>(Wq, W3q);
  convert_W<<<1024, 256, 0, stream>>>(Wk, W3k);
  convert_W1<<<1024, 256, 0, stream>>>(Wv, W1v);
  convert_W<<<1024, 256, 0, stream>>>(Wo, W3o);
  rope_table<<<1, 512, 0, stream>>>(cosT, sinT);
  convert_Aq<<<NTOK, 256, 0, stream>>>(src, Aqh, Aql);
  gemm_x3<<<dim3(NTOK / 128, 8), 256, 0, stream>>>(Aqh, Aql, W3q, qbuf);

  for (int c = 0; c < nchunks; ++c){
    const int mt = cn * LSEQ / 256;       // 256-row tiles
    convert_A<<<cn * LSEQ, 256, 0, stream>>>(src, Ah, Al, c * cn);
    gemm8_t<48, K3,   true,  false><<<dim3(4, mt), 512, 0, stream>>>(Ah, Al, W3k, (void*)Kb);
    gemm8_t<16, CDIM, false, true ><<<dim3(4, mt), 512, 0, stream>>>(Ah, Al, W1v, (void*)Vb);
    attn_kernel<<<cn * 4, 256, 0, stream>>>(Kb, Vb, qbuf, cosT, sinT, ohi, olo, c * cn);
  }
  gemm_x3<<<dim3(NTOK / 128, 8), 256, 0, stream>>>(ohi, olo, W3o, out);
}

// Round 8
// 658.413 us; speedup vs baseline: 1.4956x; 1.1543x over previous
//
#include <hip/hip_runtime.h>
#include <stdint.h>

typedef __attribute__((ext_vector_type(4))) float f32x4;
typedef __attribute__((ext_vector_type(8))) __bf16 bf16x8;
typedef __attribute__((ext_vector_type(4))) uint16_t u16x4;

#define CDIM 1024
#define K3   3072
#define LSEQ 13
#define NTOK 4096

__device__ __forceinline__ uint16_t f2bf(float x){
  union { float f; uint32_t u; } c; c.f = x;
  uint32_t r = (c.u + 0x7FFFu + ((c.u >> 16) & 1u)) >> 16;
  return (uint16_t)r;
}
__device__ __forceinline__ float bf2f(uint16_t h){
  union { uint32_t u; float f; } c; c.u = ((uint32_t)h) << 16;
  return c.f;
}

__device__ __forceinline__ void async16(const void* g, void* l){
  __builtin_amdgcn_global_load_lds((__attribute__((address_space(1))) void*)(g),
                                   (__attribute__((address_space(3))) void*)(l), 16, 0, 0);
}

// ---------------- conversion kernels ----------------

// W fp32 -> [1024][3072] bf16 = [hi | hi | lo]   (x3 virtual-K layout — Q, O)
__global__ void convert_W(const float* __restrict__ W, uint16_t* __restrict__ W3){
  int idx = blockIdx.x * 256 + threadIdx.x;
  int j = idx >> 8;
  int c4 = (idx & 255) * 4;
  float4 v = *(const float4*)(W + (size_t)j * CDIM + c4);
  u16x4 h, lo;
  h.x = f2bf(v.x); lo.x = f2bf(v.x - bf2f(h.x));
  h.y = f2bf(v.y); lo.y = f2bf(v.y - bf2f(h.y));
  h.z = f2bf(v.z); lo.z = f2bf(v.z - bf2f(h.z));
  h.w = f2bf(v.w); lo.w = f2bf(v.w - bf2f(h.w));
  uint16_t* r = W3 + (size_t)j * K3;
  *(u16x4*)(r + c4)        = h;
  *(u16x4*)(r + 1024 + c4) = h;
  *(u16x4*)(r + 2048 + c4) = lo;
}

// W fp32 -> [1024][2048] bf16 = [hi | hi]   (x2 virtual-K layout — K projection)
__global__ void convert_W2(const float* __restrict__ W, uint16_t* __restrict__ W2){
  int idx = blockIdx.x * 256 + threadIdx.x;
  int j = idx >> 8;
  int c4 = (idx & 255) * 4;
  float4 v = *(const float4*)(W + (size_t)j * CDIM + c4);
  u16x4 h;
  h.x = f2bf(v.x); h.y = f2bf(v.y); h.z = f2bf(v.z); h.w = f2bf(v.w);
  uint16_t* r = W2 + (size_t)j * 2048;
  *(u16x4*)(r + c4)        = h;
  *(u16x4*)(r + 1024 + c4) = h;
}

// W fp32 -> [1024][1024] bf16 hi only   (x1 layout — V projection)
__global__ void convert_W1(const float* __restrict__ W, uint16_t* __restrict__ W1){
  int idx = blockIdx.x * 256 + threadIdx.x;
  int j = idx >> 8;
  int c4 = (idx & 255) * 4;
  float4 v = *(const float4*)(W + (size_t)j * CDIM + c4);
  u16x4 h;
  h.x = f2bf(v.x); h.y = f2bf(v.y); h.z = f2bf(v.z); h.w = f2bf(v.w);
  *(u16x4*)(W1 + (size_t)j * CDIM + c4) = h;
}

__global__ void rope_table(float* __restrict__ cosT, float* __restrict__ sinT){
  int t = threadIdx.x;
  if (t < LSEQ * 32){
    int l = t >> 5, i = t & 31;
    float inv = 1.0f / powf(10000.0f, ((float)(2 * i)) / 64.0f);
    float a = (float)l * inv;
    cosT[t] = cosf(a);
    sinT[t] = sinf(a);
  }
}

__global__ void convert_A(const float* __restrict__ src, uint16_t* __restrict__ Ah,
                          uint16_t* __restrict__ Al, int n0){
  int idx = blockIdx.x * 256 + threadIdx.x;
  int row = idx >> 8;
  int c4 = (idx & 255) * 4;
  int nl = row / 13;
  int l  = row - nl * 13;
  float4 v = *(const float4*)(src + (size_t)l * (NTOK * CDIM) + (size_t)(n0 + nl) * CDIM + c4);
  u16x4 h, lo;
  h.x = f2bf(v.x); lo.x = f2bf(v.x - bf2f(h.x));
  h.y = f2bf(v.y); lo.y = f2bf(v.y - bf2f(h.y));
  h.z = f2bf(v.z); lo.z = f2bf(v.z - bf2f(h.z));
  h.w = f2bf(v.w); lo.w = f2bf(v.w - bf2f(h.w));
  *(u16x4*)(Ah + (size_t)row * CDIM + c4) = h;
  *(u16x4*)(Al + (size_t)row * CDIM + c4) = lo;
}

__global__ void convert_Aq(const float* __restrict__ src, uint16_t* __restrict__ Ah,
                           uint16_t* __restrict__ Al){
  int idx = blockIdx.x * 256 + threadIdx.x;
  int n = idx >> 8;
  int c4 = (idx & 255) * 4;
  float4 v = *(const float4*)(src + (size_t)12 * (NTOK * CDIM) + (size_t)n * CDIM + c4);
  u16x4 h, lo;
  h.x = f2bf(v.x); lo.x = f2bf(v.x - bf2f(h.x));
  h.y = f2bf(v.y); lo.y = f2bf(v.y - bf2f(h.y));
  h.z = f2bf(v.z); lo.z = f2bf(v.z - bf2f(h.z));
  h.w = f2bf(v.w); lo.w = f2bf(v.w - bf2f(h.w));
  *(u16x4*)(Ah + (size_t)n * CDIM + c4) = h;
  *(u16x4*)(Al + (size_t)n * CDIM + c4) = lo;
}

// ---------------- 128x128 bf16x3 GEMM (2-barrier structure) — Q and O projections ----------------
__global__ __launch_bounds__(256, 2)
void gemm_x3(const uint16_t* __restrict__ Ahi, const uint16_t* __restrict__ Alo,
             const uint16_t* __restrict__ B3, float* __restrict__ Cout)
{
  __shared__ __align__(16) uint16_t sA[128 * 64];
  __shared__ __align__(16) uint16_t sB[128 * 64];
  const int tid  = threadIdx.x;
  const int lane = tid & 63;
  const int wave = tid >> 6;
  const int arow0 = blockIdx.x * 128;
  const int bcol0 = blockIdx.y * 128;
  const int wr = (wave >> 1) * 64;
  const int wc = (wave & 1) * 64;

  const f32x4 fzero = {0.f, 0.f, 0.f, 0.f};
  f32x4 acc[4][4];
#pragma unroll
  for (int i = 0; i < 4; ++i)
#pragma unroll
    for (int j = 0; j < 4; ++j)
      acc[i][j] = fzero;

  size_t aOff[4], bOff[4];
  int ldsOff[4];
#pragma unroll
  for (int i = 0; i < 4; ++i){
    int o = i * 256 + tid;
    int row = o >> 3;
    int ss = (o & 7) ^ (row & 7);
    aOff[i] = (size_t)(arow0 + row) * CDIM + ss * 8;
    bOff[i] = (size_t)(bcol0 + row) * K3 + ss * 8;
    ldsOff[i] = (i * 256 + wave * 64) * 16;
  }

  int aRd[2][4], bRd[2][4];
#pragma unroll
  for (int ks = 0; ks < 2; ++ks){
    int sw = ((lane >> 4) + ks * 4) ^ (lane & 7);
#pragma unroll
    for (int mi = 0; mi < 4; ++mi){
      aRd[ks][mi] = (wr + mi * 16 + (lane & 15)) * 128 + sw * 16;
      bRd[ks][mi] = (wc + mi * 16 + (lane & 15)) * 128 + sw * 16;
    }
  }

  const char* sAc = (const char*)sA;
  const char* sBc = (const char*)sB;

  for (int step = 0; step < K3 / 64; ++step){
    const int kv0 = step * 64;
    const uint16_t* Abase = ((kv0 >> 10) == 1) ? Alo : Ahi;
    const int kr0 = kv0 & 1023;
#pragma unroll
    for (int i = 0; i < 4; ++i){
      async16(Abase + aOff[i] + kr0, (char*)sA + ldsOff[i]);
      async16(B3    + bOff[i] + kv0, (char*)sB + ldsOff[i]);
    }
    __syncthreads();
#pragma unroll
    for (int ks = 0; ks < 2; ++ks){
      bf16x8 af[4], bfr[4];
#pragma unroll
      for (int mi = 0; mi < 4; ++mi) af[mi]  = *(const bf16x8*)(sAc + aRd[ks][mi]);
#pragma unroll
      for (int ni = 0; ni < 4; ++ni) bfr[ni] = *(const bf16x8*)(sBc + bRd[ks][ni]);
#pragma unroll
      for (int mi = 0; mi < 4; ++mi)
#pragma unroll
        for (int ni = 0; ni < 4; ++ni)
          acc[mi][ni] = __builtin_amdgcn_mfma_f32_16x16x32_bf16(af[mi], bfr[ni], acc[mi][ni], 0, 0, 0);
    }
    __syncthreads();
  }

#pragma unroll
  for (int mi = 0; mi < 4; ++mi){
    const int row = arow0 + wr + mi * 16 + (lane >> 4) * 4;
#pragma unroll
    for (int r = 0; r < 4; ++r){
      float* crow = Cout + (size_t)(row + r) * CDIM + bcol0 + wc + (lane & 15);
#pragma unroll
      for (int ni = 0; ni < 4; ++ni)
        crow[ni * 16] = acc[mi][ni][r];
    }
  }
}

// ---------------- 256x256 8-phase GEMM template (T3+T4+T5) ----------------
// NSTEP: virtual-K tiles (32 = x2 [hi,lo]x[hi|hi], 16 = x1); BSTR: B row stride;
// XP: A phase switch at tt>=16 -> A_lo; OUTBF16: bf16 C store.
template<int NSTEP, int BSTR, bool XP, bool OUTBF16>
__global__ __launch_bounds__(512, 1)
void gemm8_t(const uint16_t* __restrict__ Ahi, const uint16_t* __restrict__ Alo,
             const uint16_t* __restrict__ B3, void* __restrict__ CoutV)
{
  __shared__ __align__(16) char smem[131072];   // A: [0,64K), B: [64K,128K); 32K per buf
  const int tid  = threadIdx.x;
  const int lane = tid & 63;
  const int wave = tid >> 6;        // 0..7
  const int wave_m = wave >> 2;     // 0..1 -> 128 rows each
  const int wave_n = wave & 3;      // 0..3 -> 64 cols each
  const int arow0 = blockIdx.y * 256;
  const int bcol0 = blockIdx.x * 256;

  const f32x4 fzero = {0.f, 0.f, 0.f, 0.f};
  f32x4 acc[8][4];
#pragma unroll
  for (int i = 0; i < 8; ++i)
#pragma unroll
    for (int j = 0; j < 4; ++j)
      acc[i][j] = fzero;

  const int abase0 = (wave_m * 128 + (lane & 15)) * 128;
  const int bbase0 = (wave_n * 64  + (lane & 15)) * 128;
  const int s0 = (((lane >> 4))     ^ (lane & 7)) * 16;
  const int s1 = ((4 + (lane >> 4)) ^ (lane & 7)) * 16;

  size_t aU[2][2], bU[2][2];
  int ldsU[2][2];
#pragma unroll
  for (int h = 0; h < 2; ++h)
#pragma unroll
    for (int j = 0; j < 2; ++j){
      int u = h * 1024 + (wave * 2 + j) * 64 + lane;
      int row = u >> 3;
      int ss = (u & 7) ^ (row & 7);          // pre-swizzled source slot (rule #21)
      aU[h][j] = (size_t)(arow0 + row) * CDIM + ss * 8;
      bU[h][j] = (size_t)(bcol0 + row) * BSTR + ss * 8;
      ldsU[h][j] = (h * 1024 + (wave * 2 + j) * 64) * 16;
    }

  auto stA = [&](int h, int tt, int dsel){
    const uint16_t* base = (XP && ((tt >> 4) == 1)) ? Alo : Ahi;  // x2 phases: hi,lo
    const int kr0 = XP ? ((tt * 64) & 1023) : (tt * 64);
    async16(base + aU[h][0] + kr0, smem + dsel + ldsU[h][0]);
    async16(base + aU[h][1] + kr0, smem + dsel + ldsU[h][1]);
  };
  auto stB = [&](int h, int tt, int dsel){
    const int k0 = tt * 64;
    async16(B3 + bU[h][0] + k0, smem + 65536 + dsel + ldsU[h][0]);
    async16(B3 + bU[h][1] + k0, smem + 65536 + dsel + ldsU[h][1]);
  };

#define RDA(dst, M, As) { dst[0] = *(const bf16x8*)((As) + abase0 + (M)*2048 + s0); \
                          dst[1] = *(const bf16x8*)((As) + abase0 + (M)*2048 + s1); }
#define MM(MI, AF) { _Pragma("unroll") for (int n = 0; n < 4; ++n){ \
    acc[MI][n] = __builtin_amdgcn_mfma_f32_16x16x32_bf16(AF[0], bf[n][0], acc[MI][n], 0, 0, 0); \
    acc[MI][n] = __builtin_amdgcn_mfma_f32_16x16x32_bf16(AF[1], bf[n][1], acc[MI][n], 0, 0, 0); } }

  // prologue: tile0 {B0,B1,A0,A1} -> buf0; tile1 {B0,B1,A0} -> buf1  (A1[1] lands in t=0 ph0)
  stB(0, 0, 0);     stB(1, 0, 0);     stA(0, 0, 0);     stA(1, 0, 0);
  stB(0, 1, 32768); stB(1, 1, 32768); stA(0, 1, 32768);
  asm volatile("s_waitcnt vmcnt(6)" ::: "memory");
  __builtin_amdgcn_sched_barrier(0);
  __builtin_amdgcn_s_barrier();

#pragma unroll 2
  for (int t = 0; t < NSTEP; ++t){
    const int sel  = (t & 1) * 32768;
    const int seln = 32768 - sel;
    const char* As = smem + sel;
    const char* Bs = smem + 65536 + sel;

    bf16x8 bf[4][2], a0[2], a1[2], a2[2], a3[2], a4[2], a5[2], a6[2], a7[2];

    // phase 0: read all B + A m0,m1; stage A1[t+1] -> other buf
#pragma unroll
    for (int n = 0; n < 4; ++n){
      bf[n][0] = *(const bf16x8*)(Bs + bbase0 + n * 2048 + s0);
      bf[n][1] = *(const bf16x8*)(Bs + bbase0 + n * 2048 + s1);
    }
    RDA(a0, 0, As); RDA(a1, 1, As);
    if (t + 1 < NSTEP) stA(1, t + 1, seln);
    __builtin_amdgcn_s_barrier();
    __builtin_amdgcn_s_setprio(1);
    MM(0, a0); MM(1, a1);
    __builtin_amdgcn_s_setprio(0);
    __builtin_amdgcn_s_barrier();

    // phase 1: read A m2..m5; stage B0[t+2]
    RDA(a2, 2, As); RDA(a3, 3, As); RDA(a4, 4, As); RDA(a5, 5, As);
    if (t + 2 < NSTEP) stB(0, t + 2, sel);
    __builtin_amdgcn_s_barrier();
    __builtin_amdgcn_s_setprio(1);
    MM(2, a2); MM(3, a3);
    __builtin_amdgcn_s_setprio(0);
    __builtin_amdgcn_s_barrier();

    // phase 2: read A m6,m7; stage B1[t+2]
    RDA(a6, 6, As); RDA(a7, 7, As);
    if (t + 2 < NSTEP) stB(1, t + 2, sel);
    __builtin_amdgcn_s_barrier();
    __builtin_amdgcn_s_setprio(1);
    MM(4, a4); MM(5, a5);
    __builtin_amdgcn_s_setprio(0);
    asm volatile("s_waitcnt lgkmcnt(0)" ::: "memory");  // a6,a7 in-register before A0 restage
    __builtin_amdgcn_sched_barrier(0);
    __builtin_amdgcn_s_barrier();

    // phase 3: stage A0[t+2]; counted vmcnt at K-tile boundary
    if (t + 2 < NSTEP) stA(0, t + 2, sel);
    if (t <= NSTEP - 3) { asm volatile("s_waitcnt vmcnt(6)" ::: "memory"); }
    else                { asm volatile("s_waitcnt vmcnt(0)" ::: "memory"); }
    __builtin_amdgcn_sched_barrier(0);
    __builtin_amdgcn_s_barrier();
    __builtin_amdgcn_s_setprio(1);
    MM(6, a6); MM(7, a7);
    __builtin_amdgcn_s_setprio(0);
    __builtin_amdgcn_s_barrier();
  }
#undef RDA
#undef MM

#pragma unroll
  for (int mi = 0; mi < 8; ++mi){
    const int row = arow0 + wave_m * 128 + mi * 16 + (lane >> 4) * 4;
#pragma unroll
    for (int r = 0; r < 4; ++r){
      const size_t co = (size_t)(row + r) * CDIM + bcol0 + wave_n * 64 + (lane & 15);
      if constexpr (OUTBF16){
        uint16_t* crow = (uint16_t*)CoutV + co;
#pragma unroll
        for (int ni = 0; ni < 4; ++ni)
          crow[ni * 16] = f2bf(acc[mi][ni][r]);
      } else {
        float* crow = (float*)CoutV + co;
#pragma unroll
        for (int ni = 0; ni < 4; ++ni)
          crow[ni * 16] = acc[mi][ni][r];
      }
    }
  }
}

// ---------------- fused RoPE + attention (l = 12 query only) ----------------
__global__ void attn_kernel(const float* __restrict__ Kb, const uint16_t* __restrict__ Vb,
                            const float* __restrict__ q, const float* __restrict__ cosT,
                            const float* __restrict__ sinT, uint16_t* __restrict__ ohi,
                            uint16_t* __restrict__ olo, int n0)
{
  int wid  = blockIdx.x * 4 + (threadIdx.x >> 6);
  int lane = threadIdx.x & 63;
  int nl = wid >> 4;
  int h  = wid & 15;
  int d = lane, i = d & 31;

  size_t qoff = (size_t)(n0 + nl) * CDIM + h * 64 + d;
  float qv = q[qoff];
  float qp = __shfl_xor(qv, 32);
  float cq = cosT[12 * 32 + i], sq = sinT[12 * 32 + i];
  float qr = (d < 32) ? (qv * cq - qp * sq) : (qv * cq + qp * sq);

  const float*    Kp = Kb + (size_t)nl * (LSEQ * CDIM) + h * 64 + d;
  const uint16_t* Vp = Vb + (size_t)nl * (LSEQ * CDIM) + h * 64 + d;

  float s[LSEQ];
#pragma unroll
  for (int m = 0; m < LSEQ; ++m){
    float kv = Kp[m * CDIM];
    float kp = __shfl_xor(kv, 32);
    float cm = cosT[m * 32 + i], sm = sinT[m * 32 + i];
    float kr = (d < 32) ? (kv * cm - kp * sm) : (kv * cm + kp * sm);
    float p = qr * kr;
    p += __shfl_xor(p, 32); p += __shfl_xor(p, 16); p += __shfl_xor(p, 8);
    p += __shfl_xor(p, 4);  p += __shfl_xor(p, 2);  p += __shfl_xor(p, 1);
    s[m] = p * 0.125f;
  }
  float mx = s[0];
#pragma unroll
  for (int m = 1; m < LSEQ; ++m) mx = fmaxf(mx, s[m]);
  float sum = 0.f;
#pragma unroll
  for (int m = 0; m < LSEQ; ++m){ s[m] = expf(s[m] - mx); sum += s[m]; }
  float inv = 1.0f / sum;
  float o = 0.f;
#pragma unroll
  for (int m = 0; m < LSEQ; ++m) o += s[m] * bf2f(Vp[m * CDIM]);
  o *= inv;
  uint16_t hb = f2bf(o);
  uint16_t lb = f2bf(o - bf2f(hb));
  ohi[qoff] = hb;
  olo[qoff] = lb;
}

// ---------------- host ----------------
extern "C" void kernel_launch(void* const* d_in, const int* in_sizes, int n_in,
                              void* d_out, int out_size, void* d_ws, size_t ws_size,
                              hipStream_t stream)
{
  (void)in_sizes; (void)n_in; (void)out_size;
  const float* src = (const float*)d_in[0];
  const float* Wq  = (const float*)d_in[1];
  const float* Wk  = (const float*)d_in[2];
  const float* Wv  = (const float*)d_in[3];
  const float* Wo  = (const float*)d_in[4];
  float* out = (float*)d_out;

  // adaptive chunk (cn multiple of 256 so cn*13 divides by 256-row tiles)
  int cn = 4096;
  while (cn > 256 && (76000000ull + (size_t)cn * 133120ull) > ws_size) cn >>= 1;
  const int nchunks = NTOK / cn;

  char* p = (char*)d_ws;
  auto carve = [&](size_t bytes) -> void* {
    void* r = (void*)p; p += (bytes + 255) & ~(size_t)255; return r;
  };
  uint16_t* W3q = (uint16_t*)carve((size_t)CDIM * K3 * 2);
  uint16_t* W2k = (uint16_t*)carve((size_t)CDIM * 2048 * 2);
  uint16_t* W1v = (uint16_t*)carve((size_t)CDIM * CDIM * 2);
  uint16_t* W3o = (uint16_t*)carve((size_t)CDIM * K3 * 2);
  float* cosT = (float*)carve(LSEQ * 32 * 4);
  float* sinT = (float*)carve(LSEQ * 32 * 4);
  uint16_t* Aqh = (uint16_t*)carve((size_t)NTOK * CDIM * 2);
  uint16_t* Aql = (uint16_t*)carve((size_t)NTOK * CDIM * 2);
  float* qbuf   = (float*)carve((size_t)NTOK * CDIM * 4);
  uint16_t* ohi = (uint16_t*)carve((size_t)NTOK * CDIM * 2);
  uint16_t* olo = (uint16_t*)carve((size_t)NTOK * CDIM * 2);
  uint16_t* Ah  = (uint16_t*)carve((size_t)cn * LSEQ * CDIM * 2);
  uint16_t* Al  = (uint16_t*)carve((size_t)cn * LSEQ * CDIM * 2);
  float* Kb     = (float*)carve((size_t)cn * LSEQ * CDIM * 4);
  uint16_t* Vb  = (uint16_t*)carve((size_t)cn * LSEQ * CDIM * 2);

  convert_W<<<1024, 256, 0, stream>>>(Wq, W3q);
  convert_W2<<<1024, 256, 0, stream>>>(Wk, W2k);
  convert_W1<<<1024, 256, 0, stream>>>(Wv, W1v);
  convert_W<<<1024, 256, 0, stream>>>(Wo, W3o);
  rope_table<<<1, 512, 0, stream>>>(cosT, sinT);
  convert_Aq<<<NTOK, 256, 0, stream>>>(src, Aqh, Aql);
  gemm_x3<<<dim3(NTOK / 128, 8), 256, 0, stream>>>(Aqh, Aql, W3q, qbuf);

  for (int c = 0; c < nchunks; ++c){
    const int mt = cn * LSEQ / 256;       // 256-row tiles
    convert_A<<<cn * LSEQ, 256, 0, stream>>>(src, Ah, Al, c * cn);
    gemm8_t<32, 2048, true,  false><<<dim3(4, mt), 512, 0, stream>>>(Ah, Al, W2k, (void*)Kb);
    gemm8_t<16, CDIM, false, true ><<<dim3(4, mt), 512, 0, stream>>>(Ah, Al, W1v, (void*)Vb);
    attn_kernel<<<cn * 4, 256, 0, stream>>>(Kb, Vb, qbuf, cosT, sinT, ohi, olo, c * cn);
  }
  gemm_x3<<<dim3(NTOK / 128, 8), 256, 0, stream>>>(ohi, olo, W3o, out);
}

// Round 9
// 500.552 us; speedup vs baseline: 1.9673x; 1.3154x over previous
//
#include <hip/hip_runtime.h>
#include <stdint.h>

typedef __attribute__((ext_vector_type(4))) float f32x4;
typedef __attribute__((ext_vector_type(8))) __bf16 bf16x8;
typedef __attribute__((ext_vector_type(4))) uint16_t u16x4;

#define CDIM 1024
#define K3   3072
#define LSEQ 13
#define NTOK 4096

__device__ __forceinline__ uint16_t f2bf(float x){
  union { float f; uint32_t u; } c; c.f = x;
  uint32_t r = (c.u + 0x7FFFu + ((c.u >> 16) & 1u)) >> 16;
  return (uint16_t)r;
}
__device__ __forceinline__ float bf2f(uint16_t h){
  union { uint32_t u; float f; } c; c.u = ((uint32_t)h) << 16;
  return c.f;
}

__device__ __forceinline__ void async16(const void* g, void* l){
  __builtin_amdgcn_global_load_lds((__attribute__((address_space(1))) void*)(g),
                                   (__attribute__((address_space(3))) void*)(l), 16, 0, 0);
}

// ---------------- conversion kernels ----------------

// W fp32 -> [1024][3072] bf16 = [hi | hi | lo]   (x3 virtual-K layout — Q, O)
__global__ void convert_W(const float* __restrict__ W, uint16_t* __restrict__ W3){
  int idx = blockIdx.x * 256 + threadIdx.x;
  int j = idx >> 8;
  int c4 = (idx & 255) * 4;
  float4 v = *(const float4*)(W + (size_t)j * CDIM + c4);
  u16x4 h, lo;
  h.x = f2bf(v.x); lo.x = f2bf(v.x - bf2f(h.x));
  h.y = f2bf(v.y); lo.y = f2bf(v.y - bf2f(h.y));
  h.z = f2bf(v.z); lo.z = f2bf(v.z - bf2f(h.z));
  h.w = f2bf(v.w); lo.w = f2bf(v.w - bf2f(h.w));
  uint16_t* r = W3 + (size_t)j * K3;
  *(u16x4*)(r + c4)        = h;
  *(u16x4*)(r + 1024 + c4) = h;
  *(u16x4*)(r + 2048 + c4) = lo;
}

// W fp32 -> [1024][1024] bf16 hi only  (x1 layout — K and V projections)
__global__ void convert_W1(const float* __restrict__ W, uint16_t* __restrict__ W1){
  int idx = blockIdx.x * 256 + threadIdx.x;
  int j = idx >> 8;
  int c4 = (idx & 255) * 4;
  float4 v = *(const float4*)(W + (size_t)j * CDIM + c4);
  u16x4 h;
  h.x = f2bf(v.x); h.y = f2bf(v.y); h.z = f2bf(v.z); h.w = f2bf(v.w);
  *(u16x4*)(W1 + (size_t)j * CDIM + c4) = h;
}

__global__ void rope_table(float* __restrict__ cosT, float* __restrict__ sinT){
  int t = threadIdx.x;
  if (t < LSEQ * 32){
    int l = t >> 5, i = t & 31;
    float inv = 1.0f / powf(10000.0f, ((float)(2 * i)) / 64.0f);
    float a = (float)l * inv;
    cosT[t] = cosf(a);
    sinT[t] = sinf(a);
  }
}

// chunk A rows (n_local*13 + l) -> bf16 hi only (K,V are x1 now)
__global__ void convert_A(const float* __restrict__ src, uint16_t* __restrict__ Ah, int n0){
  int idx = blockIdx.x * 256 + threadIdx.x;
  int row = idx >> 8;
  int c4 = (idx & 255) * 4;
  int nl = row / 13;
  int l  = row - nl * 13;
  float4 v = *(const float4*)(src + (size_t)l * (NTOK * CDIM) + (size_t)(n0 + nl) * CDIM + c4);
  u16x4 h;
  h.x = f2bf(v.x); h.y = f2bf(v.y); h.z = f2bf(v.z); h.w = f2bf(v.w);
  *(u16x4*)(Ah + (size_t)row * CDIM + c4) = h;
}

__global__ void convert_Aq(const float* __restrict__ src, uint16_t* __restrict__ Ah,
                           uint16_t* __restrict__ Al){
  int idx = blockIdx.x * 256 + threadIdx.x;
  int n = idx >> 8;
  int c4 = (idx & 255) * 4;
  float4 v = *(const float4*)(src + (size_t)12 * (NTOK * CDIM) + (size_t)n * CDIM + c4);
  u16x4 h, lo;
  h.x = f2bf(v.x); lo.x = f2bf(v.x - bf2f(h.x));
  h.y = f2bf(v.y); lo.y = f2bf(v.y - bf2f(h.y));
  h.z = f2bf(v.z); lo.z = f2bf(v.z - bf2f(h.z));
  h.w = f2bf(v.w); lo.w = f2bf(v.w - bf2f(h.w));
  *(u16x4*)(Ah + (size_t)n * CDIM + c4) = h;
  *(u16x4*)(Al + (size_t)n * CDIM + c4) = lo;
}

// ---------------- 128x128 bf16x3 GEMM (2-barrier structure) — Q and O projections ----------------
__global__ __launch_bounds__(256, 2)
void gemm_x3(const uint16_t* __restrict__ Ahi, const uint16_t* __restrict__ Alo,
             const uint16_t* __restrict__ B3, float* __restrict__ Cout)
{
  __shared__ __align__(16) uint16_t sA[128 * 64];
  __shared__ __align__(16) uint16_t sB[128 * 64];
  const int tid  = threadIdx.x;
  const int lane = tid & 63;
  const int wave = tid >> 6;
  const int arow0 = blockIdx.x * 128;
  const int bcol0 = blockIdx.y * 128;
  const int wr = (wave >> 1) * 64;
  const int wc = (wave & 1) * 64;

  const f32x4 fzero = {0.f, 0.f, 0.f, 0.f};
  f32x4 acc[4][4];
#pragma unroll
  for (int i = 0; i < 4; ++i)
#pragma unroll
    for (int j = 0; j < 4; ++j)
      acc[i][j] = fzero;

  size_t aOff[4], bOff[4];
  int ldsOff[4];
#pragma unroll
  for (int i = 0; i < 4; ++i){
    int o = i * 256 + tid;
    int row = o >> 3;
    int ss = (o & 7) ^ (row & 7);
    aOff[i] = (size_t)(arow0 + row) * CDIM + ss * 8;
    bOff[i] = (size_t)(bcol0 + row) * K3 + ss * 8;
    ldsOff[i] = (i * 256 + wave * 64) * 16;
  }

  int aRd[2][4], bRd[2][4];
#pragma unroll
  for (int ks = 0; ks < 2; ++ks){
    int sw = ((lane >> 4) + ks * 4) ^ (lane & 7);
#pragma unroll
    for (int mi = 0; mi < 4; ++mi){
      aRd[ks][mi] = (wr + mi * 16 + (lane & 15)) * 128 + sw * 16;
      bRd[ks][mi] = (wc + mi * 16 + (lane & 15)) * 128 + sw * 16;
    }
  }

  const char* sAc = (const char*)sA;
  const char* sBc = (const char*)sB;

  for (int step = 0; step < K3 / 64; ++step){
    const int kv0 = step * 64;
    const uint16_t* Abase = ((kv0 >> 10) == 1) ? Alo : Ahi;
    const int kr0 = kv0 & 1023;
#pragma unroll
    for (int i = 0; i < 4; ++i){
      async16(Abase + aOff[i] + kr0, (char*)sA + ldsOff[i]);
      async16(B3    + bOff[i] + kv0, (char*)sB + ldsOff[i]);
    }
    __syncthreads();
#pragma unroll
    for (int ks = 0; ks < 2; ++ks){
      bf16x8 af[4], bfr[4];
#pragma unroll
      for (int mi = 0; mi < 4; ++mi) af[mi]  = *(const bf16x8*)(sAc + aRd[ks][mi]);
#pragma unroll
      for (int ni = 0; ni < 4; ++ni) bfr[ni] = *(const bf16x8*)(sBc + bRd[ks][ni]);
#pragma unroll
      for (int mi = 0; mi < 4; ++mi)
#pragma unroll
        for (int ni = 0; ni < 4; ++ni)
          acc[mi][ni] = __builtin_amdgcn_mfma_f32_16x16x32_bf16(af[mi], bfr[ni], acc[mi][ni], 0, 0, 0);
    }
    __syncthreads();
  }

#pragma unroll
  for (int mi = 0; mi < 4; ++mi){
    const int row = arow0 + wr + mi * 16 + (lane >> 4) * 4;
#pragma unroll
    for (int r = 0; r < 4; ++r){
      float* crow = Cout + (size_t)(row + r) * CDIM + bcol0 + wc + (lane & 15);
#pragma unroll
      for (int ni = 0; ni < 4; ++ni)
        crow[ni * 16] = acc[mi][ni][r];
    }
  }
}

// ---------------- 256x256 8-phase x1 GEMM, merged K|V panel, bf16 out ----------------
// 16 K-steps; B = W1kv [2048][1024] (rows 0..1023 K cols, 1024..2047 V cols).
// grid (8, mt) x-fastest: 8 col-blocks of one row-tile round-robin the 8 XCDs.
__global__ __launch_bounds__(512, 1)
void gemm8_kv(const uint16_t* __restrict__ Ahi, const uint16_t* __restrict__ B1,
              uint16_t* __restrict__ Kout, uint16_t* __restrict__ Vout)
{
  constexpr int NSTEP = 16;
  __shared__ __align__(16) char smem[131072];   // A: [0,64K), B: [64K,128K); 32K per buf
  const int tid  = threadIdx.x;
  const int lane = tid & 63;
  const int wave = tid >> 6;        // 0..7
  const int wave_m = wave >> 2;     // 0..1 -> 128 rows each
  const int wave_n = wave & 3;      // 0..3 -> 64 cols each
  const int arow0 = blockIdx.y * 256;
  const int gcol  = blockIdx.x * 256;           // 0..1792 within [K|V] panel
  uint16_t* Cout = (gcol < 1024) ? Kout : Vout;
  const int bcol0 = gcol & 1023;

  const f32x4 fzero = {0.f, 0.f, 0.f, 0.f};
  f32x4 acc[8][4];
#pragma unroll
  for (int i = 0; i < 8; ++i)
#pragma unroll
    for (int j = 0; j < 4; ++j)
      acc[i][j] = fzero;

  const int abase0 = (wave_m * 128 + (lane & 15)) * 128;
  const int bbase0 = (wave_n * 64  + (lane & 15)) * 128;
  const int s0 = (((lane >> 4))     ^ (lane & 7)) * 16;
  const int s1 = ((4 + (lane >> 4)) ^ (lane & 7)) * 16;

  size_t aU[2][2], bU[2][2];
  int ldsU[2][2];
#pragma unroll
  for (int h = 0; h < 2; ++h)
#pragma unroll
    for (int j = 0; j < 2; ++j){
      int u = h * 1024 + (wave * 2 + j) * 64 + lane;
      int row = u >> 3;
      int ss = (u & 7) ^ (row & 7);          // pre-swizzled source slot (rule #21)
      aU[h][j] = (size_t)(arow0 + row) * CDIM + ss * 8;
      bU[h][j] = (size_t)(gcol  + row) * CDIM + ss * 8;
      ldsU[h][j] = (h * 1024 + (wave * 2 + j) * 64) * 16;
    }

  auto stA = [&](int h, int tt, int dsel){
    const int k0 = tt * 64;
    async16(Ahi + aU[h][0] + k0, smem + dsel + ldsU[h][0]);
    async16(Ahi + aU[h][1] + k0, smem + dsel + ldsU[h][1]);
  };
  auto stB = [&](int h, int tt, int dsel){
    const int k0 = tt * 64;
    async16(B1 + bU[h][0] + k0, smem + 65536 + dsel + ldsU[h][0]);
    async16(B1 + bU[h][1] + k0, smem + 65536 + dsel + ldsU[h][1]);
  };

#define RDA(dst, M, As) { dst[0] = *(const bf16x8*)((As) + abase0 + (M)*2048 + s0); \
                          dst[1] = *(const bf16x8*)((As) + abase0 + (M)*2048 + s1); }
#define MM(MI, AF) { _Pragma("unroll") for (int n = 0; n < 4; ++n){ \
    acc[MI][n] = __builtin_amdgcn_mfma_f32_16x16x32_bf16(AF[0], bf[n][0], acc[MI][n], 0, 0, 0); \
    acc[MI][n] = __builtin_amdgcn_mfma_f32_16x16x32_bf16(AF[1], bf[n][1], acc[MI][n], 0, 0, 0); } }

  // prologue: tile0 {B0,B1,A0,A1} -> buf0; tile1 {B0,B1,A0} -> buf1  (A1[1] lands in t=0 ph0)
  stB(0, 0, 0);     stB(1, 0, 0);     stA(0, 0, 0);     stA(1, 0, 0);
  stB(0, 1, 32768); stB(1, 1, 32768); stA(0, 1, 32768);
  asm volatile("s_waitcnt vmcnt(6)" ::: "memory");
  __builtin_amdgcn_sched_barrier(0);
  __builtin_amdgcn_s_barrier();

#pragma unroll 2
  for (int t = 0; t < NSTEP; ++t){
    const int sel  = (t & 1) * 32768;
    const int seln = 32768 - sel;
    const char* As = smem + sel;
    const char* Bs = smem + 65536 + sel;

    bf16x8 bf[4][2], a0[2], a1[2], a2[2], a3[2], a4[2], a5[2], a6[2], a7[2];

    // phase 0: read all B + A m0,m1; stage A1[t+1] -> other buf
#pragma unroll
    for (int n = 0; n < 4; ++n){
      bf[n][0] = *(const bf16x8*)(Bs + bbase0 + n * 2048 + s0);
      bf[n][1] = *(const bf16x8*)(Bs + bbase0 + n * 2048 + s1);
    }
    RDA(a0, 0, As); RDA(a1, 1, As);
    if (t + 1 < NSTEP) stA(1, t + 1, seln);
    __builtin_amdgcn_s_barrier();
    __builtin_amdgcn_s_setprio(1);
    MM(0, a0); MM(1, a1);
    __builtin_amdgcn_s_setprio(0);
    __builtin_amdgcn_s_barrier();

    // phase 1: read A m2..m5; stage B0[t+2]
    RDA(a2, 2, As); RDA(a3, 3, As); RDA(a4, 4, As); RDA(a5, 5, As);
    if (t + 2 < NSTEP) stB(0, t + 2, sel);
    __builtin_amdgcn_s_barrier();
    __builtin_amdgcn_s_setprio(1);
    MM(2, a2); MM(3, a3);
    __builtin_amdgcn_s_setprio(0);
    __builtin_amdgcn_s_barrier();

    // phase 2: read A m6,m7; stage B1[t+2]
    RDA(a6, 6, As); RDA(a7, 7, As);
    if (t + 2 < NSTEP) stB(1, t + 2, sel);
    __builtin_amdgcn_s_barrier();
    __builtin_amdgcn_s_setprio(1);
    MM(4, a4); MM(5, a5);
    __builtin_amdgcn_s_setprio(0);
    asm volatile("s_waitcnt lgkmcnt(0)" ::: "memory");  // a6,a7 in-register before A0 restage
    __builtin_amdgcn_sched_barrier(0);
    __builtin_amdgcn_s_barrier();

    // phase 3: stage A0[t+2]; counted vmcnt at K-tile boundary
    if (t + 2 < NSTEP) stA(0, t + 2, sel);
    if (t <= NSTEP - 3) { asm volatile("s_waitcnt vmcnt(6)" ::: "memory"); }
    else                { asm volatile("s_waitcnt vmcnt(0)" ::: "memory"); }
    __builtin_amdgcn_sched_barrier(0);
    __builtin_amdgcn_s_barrier();
    __builtin_amdgcn_s_setprio(1);
    MM(6, a6); MM(7, a7);
    __builtin_amdgcn_s_setprio(0);
    __builtin_amdgcn_s_barrier();
  }
#undef RDA
#undef MM

#pragma unroll
  for (int mi = 0; mi < 8; ++mi){
    const int row = arow0 + wave_m * 128 + mi * 16 + (lane >> 4) * 4;
#pragma unroll
    for (int r = 0; r < 4; ++r){
      uint16_t* crow = Cout + (size_t)(row + r) * CDIM + bcol0 + wave_n * 64 + (lane & 15);
#pragma unroll
      for (int ni = 0; ni < 4; ++ni)
        crow[ni * 16] = f2bf(acc[mi][ni][r]);
    }
  }
}

// ---------------- fused RoPE + attention (l = 12 query only) ----------------
__global__ void attn_kernel(const uint16_t* __restrict__ Kb, const uint16_t* __restrict__ Vb,
                            const float* __restrict__ q, const float* __restrict__ cosT,
                            const float* __restrict__ sinT, uint16_t* __restrict__ ohi,
                            uint16_t* __restrict__ olo, int n0)
{
  int wid  = blockIdx.x * 4 + (threadIdx.x >> 6);
  int lane = threadIdx.x & 63;
  int nl = wid >> 4;
  int h  = wid & 15;
  int d = lane, i = d & 31;

  size_t qoff = (size_t)(n0 + nl) * CDIM + h * 64 + d;
  float qv = q[qoff];
  float qp = __shfl_xor(qv, 32);
  float cq = cosT[12 * 32 + i], sq = sinT[12 * 32 + i];
  float qr = (d < 32) ? (qv * cq - qp * sq) : (qv * cq + qp * sq);

  const uint16_t* Kp = Kb + (size_t)nl * (LSEQ * CDIM) + h * 64 + d;
  const uint16_t* Vp = Vb + (size_t)nl * (LSEQ * CDIM) + h * 64 + d;

  float s[LSEQ];
#pragma unroll
  for (int m = 0; m < LSEQ; ++m){
    float kv = bf2f(Kp[m * CDIM]);
    float kp = __shfl_xor(kv, 32);
    float cm = cosT[m * 32 + i], sm = sinT[m * 32 + i];
    float kr = (d < 32) ? (kv * cm - kp * sm) : (kv * cm + kp * sm);
    float p = qr * kr;
    p += __shfl_xor(p, 32); p += __shfl_xor(p, 16); p += __shfl_xor(p, 8);
    p += __shfl_xor(p, 4);  p += __shfl_xor(p, 2);  p += __shfl_xor(p, 1);
    s[m] = p * 0.125f;
  }
  float mx = s[0];
#pragma unroll
  for (int m = 1; m < LSEQ; ++m) mx = fmaxf(mx, s[m]);
  float sum = 0.f;
#pragma unroll
  for (int m = 0; m < LSEQ; ++m){ s[m] = expf(s[m] - mx); sum += s[m]; }
  float inv = 1.0f / sum;
  float o = 0.f;
#pragma unroll
  for (int m = 0; m < LSEQ; ++m) o += s[m] * bf2f(Vp[m * CDIM]);
  o *= inv;
  uint16_t hb = f2bf(o);
  uint16_t lb = f2bf(o - bf2f(hb));
  ohi[qoff] = hb;
  olo[qoff] = lb;
}

// ---------------- host ----------------
extern "C" void kernel_launch(void* const* d_in, const int* in_sizes, int n_in,
                              void* d_out, int out_size, void* d_ws, size_t ws_size,
                              hipStream_t stream)
{
  (void)in_sizes; (void)n_in; (void)out_size;
  const float* src = (const float*)d_in[0];
  const float* Wq  = (const float*)d_in[1];
  const float* Wk  = (const float*)d_in[2];
  const float* Wv  = (const float*)d_in[3];
  const float* Wo  = (const float*)d_in[4];
  float* out = (float*)d_out;

  // adaptive chunk (cn multiple of 256 so cn*13 divides by 256-row tiles)
  int cn = 4096;
  while (cn > 256 && (60000000ull + (size_t)cn * 79872ull) > ws_size) cn >>= 1;
  const int nchunks = NTOK / cn;

  char* p = (char*)d_ws;
  auto carve = [&](size_t bytes) -> void* {
    void* r = (void*)p; p += (bytes + 255) & ~(size_t)255; return r;
  };
  uint16_t* W3q  = (uint16_t*)carve((size_t)CDIM * K3 * 2);
  uint16_t* W1kv = (uint16_t*)carve((size_t)2 * CDIM * CDIM * 2);  // rows 0..1023 K, 1024..2047 V
  uint16_t* W3o  = (uint16_t*)carve((size_t)CDIM * K3 * 2);
  float* cosT = (float*)carve(LSEQ * 32 * 4);
  float* sinT = (float*)carve(LSEQ * 32 * 4);
  uint16_t* Aqh = (uint16_t*)carve((size_t)NTOK * CDIM * 2);
  uint16_t* Aql = (uint16_t*)carve((size_t)NTOK * CDIM * 2);
  float* qbuf   = (float*)carve((size_t)NTOK * CDIM * 4);
  uint16_t* ohi = (uint16_t*)carve((size_t)NTOK * CDIM * 2);
  uint16_t* olo = (uint16_t*)carve((size_t)NTOK * CDIM * 2);
  uint16_t* Ah  = (uint16_t*)carve((size_t)cn * LSEQ * CDIM * 2);
  uint16_t* Kb  = (uint16_t*)carve((size_t)cn * LSEQ * CDIM * 2);
  uint16_t* Vb  = (uint16_t*)carve((size_t)cn * LSEQ * CDIM * 2);

  convert_W<<<1024, 256, 0, stream>>>(Wq, W3q);
  convert_W1<<<1024, 256, 0, stream>>>(Wk, W1kv);
  convert_W1<<<1024, 256, 0, stream>>>(Wv, W1kv + (size_t)CDIM * CDIM);
  convert_W<<<1024, 256, 0, stream>>>(Wo, W3o);
  rope_table<<<1, 512, 0, stream>>>(cosT, sinT);
  convert_Aq<<<NTOK, 256, 0, stream>>>(src, Aqh, Aql);
  gemm_x3<<<dim3(NTOK / 128, 8), 256, 0, stream>>>(Aqh, Aql, W3q, qbuf);

  for (int c = 0; c < nchunks; ++c){
    const int mt = cn * LSEQ / 256;       // 256-row tiles
    convert_A<<<cn * LSEQ, 256, 0, stream>>>(src, Ah, c * cn);
    gemm8_kv<<<dim3(8, mt), 512, 0, stream>>>(Ah, W1kv, Kb, Vb);
    attn_kernel<<<cn * 4, 256, 0, stream>>>(Kb, Vb, qbuf, cosT, sinT, ohi, olo, c * cn);
  }
  gemm_x3<<<dim3(NTOK / 128, 8), 256, 0, stream>>>(ohi, olo, W3o, out);
}

// Round 10
// 427.497 us; speedup vs baseline: 2.3035x; 1.1709x over previous
//
#include <hip/hip_runtime.h>
#include <stdint.h>

typedef __attribute__((ext_vector_type(4))) float f32x4;
typedef __attribute__((ext_vector_type(8))) __bf16 bf16x8;
typedef __attribute__((ext_vector_type(4))) uint16_t u16x4;

#define CDIM 1024
#define LSEQ 13
#define NTOK 4096

__device__ __forceinline__ uint16_t f2bf(float x){
  union { float f; uint32_t u; } c; c.f = x;
  uint32_t r = (c.u + 0x7FFFu + ((c.u >> 16) & 1u)) >> 16;
  return (uint16_t)r;
}
__device__ __forceinline__ float bf2f(uint16_t h){
  union { uint32_t u; float f; } c; c.u = ((uint32_t)h) << 16;
  return c.f;
}

__device__ __forceinline__ void async16(const void* g, void* l){
  __builtin_amdgcn_global_load_lds((__attribute__((address_space(1))) void*)(g),
                                   (__attribute__((address_space(3))) void*)(l), 16, 0, 0);
}

// ---------------- conversion kernels ----------------

// W fp32 -> [1024][1024] bf16 hi  (x1 layout — all projections)
__global__ void convert_W1(const float* __restrict__ W, uint16_t* __restrict__ W1){
  int idx = blockIdx.x * 256 + threadIdx.x;
  int j = idx >> 8;
  int c4 = (idx & 255) * 4;
  float4 v = *(const float4*)(W + (size_t)j * CDIM + c4);
  u16x4 h;
  h.x = f2bf(v.x); h.y = f2bf(v.y); h.z = f2bf(v.z); h.w = f2bf(v.w);
  *(u16x4*)(W1 + (size_t)j * CDIM + c4) = h;
}

__global__ void rope_table(float* __restrict__ cosT, float* __restrict__ sinT){
  int t = threadIdx.x;
  if (t < LSEQ * 32){
    int l = t >> 5, i = t & 31;
    float inv = 1.0f / powf(10000.0f, ((float)(2 * i)) / 64.0f);
    float a = (float)l * inv;
    cosT[t] = cosf(a);
    sinT[t] = sinf(a);
  }
}

// chunk A rows (n_local*13 + l) -> bf16 hi
__global__ void convert_A(const float* __restrict__ src, uint16_t* __restrict__ Ah, int n0){
  int idx = blockIdx.x * 256 + threadIdx.x;
  int row = idx >> 8;
  int c4 = (idx & 255) * 4;
  int nl = row / 13;
  int l  = row - nl * 13;
  float4 v = *(const float4*)(src + (size_t)l * (NTOK * CDIM) + (size_t)(n0 + nl) * CDIM + c4);
  u16x4 h;
  h.x = f2bf(v.x); h.y = f2bf(v.y); h.z = f2bf(v.z); h.w = f2bf(v.w);
  *(u16x4*)(Ah + (size_t)row * CDIM + c4) = h;
}

// Q input rows (l = 12 only) -> bf16 hi
__global__ void convert_Aq1(const float* __restrict__ src, uint16_t* __restrict__ Ah){
  int idx = blockIdx.x * 256 + threadIdx.x;
  int n = idx >> 8;
  int c4 = (idx & 255) * 4;
  float4 v = *(const float4*)(src + (size_t)12 * (NTOK * CDIM) + (size_t)n * CDIM + c4);
  u16x4 h;
  h.x = f2bf(v.x); h.y = f2bf(v.y); h.z = f2bf(v.z); h.w = f2bf(v.w);
  *(u16x4*)(Ah + (size_t)n * CDIM + c4) = h;
}

// ---------------- 128x128 GEMM template (2-barrier m97 structure) — Q (x1) and O (x2) ----------------
// NSTEP=16: C = Ahi*B; NSTEP=32 + ALO: C = Ahi*B + Alo*B (bf16x2). B = [1024][1024] bf16.
template<int NSTEP, bool ALO>
__global__ __launch_bounds__(256, 2)
void gemm128(const uint16_t* __restrict__ Ahi, const uint16_t* __restrict__ Alo,
             const uint16_t* __restrict__ B1, float* __restrict__ Cout)
{
  __shared__ __align__(16) uint16_t sA[128 * 64];
  __shared__ __align__(16) uint16_t sB[128 * 64];
  const int tid  = threadIdx.x;
  const int lane = tid & 63;
  const int wave = tid >> 6;
  const int arow0 = blockIdx.x * 128;
  const int bcol0 = blockIdx.y * 128;
  const int wr = (wave >> 1) * 64;
  const int wc = (wave & 1) * 64;

  const f32x4 fzero = {0.f, 0.f, 0.f, 0.f};
  f32x4 acc[4][4];
#pragma unroll
  for (int i = 0; i < 4; ++i)
#pragma unroll
    for (int j = 0; j < 4; ++j)
      acc[i][j] = fzero;

  size_t aOff[4], bOff[4];
  int ldsOff[4];
#pragma unroll
  for (int i = 0; i < 4; ++i){
    int o = i * 256 + tid;
    int row = o >> 3;
    int ss = (o & 7) ^ (row & 7);
    aOff[i] = (size_t)(arow0 + row) * CDIM + ss * 8;
    bOff[i] = (size_t)(bcol0 + row) * CDIM + ss * 8;
    ldsOff[i] = (i * 256 + wave * 64) * 16;
  }

  int aRd[2][4], bRd[2][4];
#pragma unroll
  for (int ks = 0; ks < 2; ++ks){
    int sw = ((lane >> 4) + ks * 4) ^ (lane & 7);
#pragma unroll
    for (int mi = 0; mi < 4; ++mi){
      aRd[ks][mi] = (wr + mi * 16 + (lane & 15)) * 128 + sw * 16;
      bRd[ks][mi] = (wc + mi * 16 + (lane & 15)) * 128 + sw * 16;
    }
  }

  const char* sAc = (const char*)sA;
  const char* sBc = (const char*)sB;

  for (int step = 0; step < NSTEP; ++step){
    const int kr0 = (step * 64) & 1023;
    const uint16_t* Abase = (ALO && step >= 16) ? Alo : Ahi;
#pragma unroll
    for (int i = 0; i < 4; ++i){
      async16(Abase + aOff[i] + kr0, (char*)sA + ldsOff[i]);
      async16(B1    + bOff[i] + kr0, (char*)sB + ldsOff[i]);
    }
    __syncthreads();
#pragma unroll
    for (int ks = 0; ks < 2; ++ks){
      bf16x8 af[4], bfr[4];
#pragma unroll
      for (int mi = 0; mi < 4; ++mi) af[mi]  = *(const bf16x8*)(sAc + aRd[ks][mi]);
#pragma unroll
      for (int ni = 0; ni < 4; ++ni) bfr[ni] = *(const bf16x8*)(sBc + bRd[ks][ni]);
#pragma unroll
      for (int mi = 0; mi < 4; ++mi)
#pragma unroll
        for (int ni = 0; ni < 4; ++ni)
          acc[mi][ni] = __builtin_amdgcn_mfma_f32_16x16x32_bf16(af[mi], bfr[ni], acc[mi][ni], 0, 0, 0);
    }
    __syncthreads();
  }

#pragma unroll
  for (int mi = 0; mi < 4; ++mi){
    const int row = arow0 + wr + mi * 16 + (lane >> 4) * 4;
#pragma unroll
    for (int r = 0; r < 4; ++r){
      float* crow = Cout + (size_t)(row + r) * CDIM + bcol0 + wc + (lane & 15);
#pragma unroll
      for (int ni = 0; ni < 4; ++ni)
        crow[ni * 16] = acc[mi][ni][r];
    }
  }
}

// ---------------- 256x256 8-phase x1 GEMM, merged K|V panel, bf16 out ----------------
// XCD row-slab mapping: XCD i (= blockIdx.x, dispatch round-robin) owns rows
// [i*mt/8,(i+1)*mt/8); its 8 consecutive blocks share one A row-tile (L2-hit)
// while B's full 4MB cycles in L2 -> A fetched from HBM once, by one XCD only.
__global__ __launch_bounds__(512, 1)
void gemm8_kv(const uint16_t* __restrict__ Ahi, const uint16_t* __restrict__ B1,
              uint16_t* __restrict__ Kout, uint16_t* __restrict__ Vout)
{
  constexpr int NSTEP = 16;
  __shared__ __align__(16) char smem[131072];   // A: [0,64K), B: [64K,128K); 32K per buf
  const int tid  = threadIdx.x;
  const int lane = tid & 63;
  const int wave = tid >> 6;        // 0..7
  const int wave_m = wave >> 2;     // 0..1 -> 128 rows each
  const int wave_n = wave & 3;      // 0..3 -> 64 cols each

  int rowt, colt;
  if ((gridDim.y & 7) == 0){
    const int mtd8 = gridDim.y >> 3;
    rowt = blockIdx.x * mtd8 + (blockIdx.y >> 3);   // row slab per XCD
    colt = blockIdx.y & 7;                          // col cycles inner
  } else {
    rowt = blockIdx.y; colt = blockIdx.x;
  }
  const int arow0 = rowt * 256;
  const int gcol  = colt * 256;                     // 0..1792 within [K|V] panel
  uint16_t* Cout = (gcol < 1024) ? Kout : Vout;
  const int bcol0 = gcol & 1023;

  const f32x4 fzero = {0.f, 0.f, 0.f, 0.f};
  f32x4 acc[8][4];
#pragma unroll
  for (int i = 0; i < 8; ++i)
#pragma unroll
    for (int j = 0; j < 4; ++j)
      acc[i][j] = fzero;

  const int abase0 = (wave_m * 128 + (lane & 15)) * 128;
  const int bbase0 = (wave_n * 64  + (lane & 15)) * 128;
  const int s0 = (((lane >> 4))     ^ (lane & 7)) * 16;
  const int s1 = ((4 + (lane >> 4)) ^ (lane & 7)) * 16;

  size_t aU[2][2], bU[2][2];
  int ldsU[2][2];
#pragma unroll
  for (int h = 0; h < 2; ++h)
#pragma unroll
    for (int j = 0; j < 2; ++j){
      int u = h * 1024 + (wave * 2 + j) * 64 + lane;
      int row = u >> 3;
      int ss = (u & 7) ^ (row & 7);          // pre-swizzled source slot (rule #21)
      aU[h][j] = (size_t)(arow0 + row) * CDIM + ss * 8;
      bU[h][j] = (size_t)(gcol  + row) * CDIM + ss * 8;
      ldsU[h][j] = (h * 1024 + (wave * 2 + j) * 64) * 16;
    }

  auto stA = [&](int h, int tt, int dsel){
    const int k0 = tt * 64;
    async16(Ahi + aU[h][0] + k0, smem + dsel + ldsU[h][0]);
    async16(Ahi + aU[h][1] + k0, smem + dsel + ldsU[h][1]);
  };
  auto stB = [&](int h, int tt, int dsel){
    const int k0 = tt * 64;
    async16(B1 + bU[h][0] + k0, smem + 65536 + dsel + ldsU[h][0]);
    async16(B1 + bU[h][1] + k0, smem + 65536 + dsel + ldsU[h][1]);
  };

#define RDA(dst, M, As) { dst[0] = *(const bf16x8*)((As) + abase0 + (M)*2048 + s0); \
                          dst[1] = *(const bf16x8*)((As) + abase0 + (M)*2048 + s1); }
#define MM(MI, AF) { _Pragma("unroll") for (int n = 0; n < 4; ++n){ \
    acc[MI][n] = __builtin_amdgcn_mfma_f32_16x16x32_bf16(AF[0], bf[n][0], acc[MI][n], 0, 0, 0); \
    acc[MI][n] = __builtin_amdgcn_mfma_f32_16x16x32_bf16(AF[1], bf[n][1], acc[MI][n], 0, 0, 0); } }

  // prologue: tile0 {B0,B1,A0,A1} -> buf0; tile1 {B0,B1,A0} -> buf1  (A1[1] lands in t=0 ph0)
  stB(0, 0, 0);     stB(1, 0, 0);     stA(0, 0, 0);     stA(1, 0, 0);
  stB(0, 1, 32768); stB(1, 1, 32768); stA(0, 1, 32768);
  asm volatile("s_waitcnt vmcnt(6)" ::: "memory");
  __builtin_amdgcn_sched_barrier(0);
  __builtin_amdgcn_s_barrier();

#pragma unroll 2
  for (int t = 0; t < NSTEP; ++t){
    const int sel  = (t & 1) * 32768;
    const int seln = 32768 - sel;
    const char* As = smem + sel;
    const char* Bs = smem + 65536 + sel;

    bf16x8 bf[4][2], a0[2], a1[2], a2[2], a3[2], a4[2], a5[2], a6[2], a7[2];

    // phase 0: read all B + A m0,m1; stage A1[t+1] -> other buf
#pragma unroll
    for (int n = 0; n < 4; ++n){
      bf[n][0] = *(const bf16x8*)(Bs + bbase0 + n * 2048 + s0);
      bf[n][1] = *(const bf16x8*)(Bs + bbase0 + n * 2048 + s1);
    }
    RDA(a0, 0, As); RDA(a1, 1, As);
    if (t + 1 < NSTEP) stA(1, t + 1, seln);
    __builtin_amdgcn_s_barrier();
    __builtin_amdgcn_s_setprio(1);
    MM(0, a0); MM(1, a1);
    __builtin_amdgcn_s_setprio(0);
    __builtin_amdgcn_s_barrier();

    // phase 1: read A m2..m5; stage B0[t+2]
    RDA(a2, 2, As); RDA(a3, 3, As); RDA(a4, 4, As); RDA(a5, 5, As);
    if (t + 2 < NSTEP) stB(0, t + 2, sel);
    __builtin_amdgcn_s_barrier();
    __builtin_amdgcn_s_setprio(1);
    MM(2, a2); MM(3, a3);
    __builtin_amdgcn_s_setprio(0);
    __builtin_amdgcn_s_barrier();

    // phase 2: read A m6,m7; stage B1[t+2]
    RDA(a6, 6, As); RDA(a7, 7, As);
    if (t + 2 < NSTEP) stB(1, t + 2, sel);
    __builtin_amdgcn_s_barrier();
    __builtin_amdgcn_s_setprio(1);
    MM(4, a4); MM(5, a5);
    __builtin_amdgcn_s_setprio(0);
    asm volatile("s_waitcnt lgkmcnt(0)" ::: "memory");  // a6,a7 in-register before A0 restage
    __builtin_amdgcn_sched_barrier(0);
    __builtin_amdgcn_s_barrier();

    // phase 3: stage A0[t+2]; counted vmcnt at K-tile boundary
    if (t + 2 < NSTEP) stA(0, t + 2, sel);
    if (t <= NSTEP - 3) { asm volatile("s_waitcnt vmcnt(6)" ::: "memory"); }
    else                { asm volatile("s_waitcnt vmcnt(0)" ::: "memory"); }
    __builtin_amdgcn_sched_barrier(0);
    __builtin_amdgcn_s_barrier();
    __builtin_amdgcn_s_setprio(1);
    MM(6, a6); MM(7, a7);
    __builtin_amdgcn_s_setprio(0);
    __builtin_amdgcn_s_barrier();
  }
#undef RDA
#undef MM

#pragma unroll
  for (int mi = 0; mi < 8; ++mi){
    const int row = arow0 + wave_m * 128 + mi * 16 + (lane >> 4) * 4;
#pragma unroll
    for (int r = 0; r < 4; ++r){
      uint16_t* crow = Cout + (size_t)(row + r) * CDIM + bcol0 + wave_n * 64 + (lane & 15);
#pragma unroll
      for (int ni = 0; ni < 4; ++ni)
        crow[ni * 16] = f2bf(acc[mi][ni][r]);
    }
  }
}

// ---------------- fused RoPE + attention (l = 12 query only) ----------------
__global__ void attn_kernel(const uint16_t* __restrict__ Kb, const uint16_t* __restrict__ Vb,
                            const float* __restrict__ q, const float* __restrict__ cosT,
                            const float* __restrict__ sinT, uint16_t* __restrict__ ohi,
                            uint16_t* __restrict__ olo, int n0)
{
  int wid  = blockIdx.x * 4 + (threadIdx.x >> 6);
  int lane = threadIdx.x & 63;
  int nl = wid >> 4;
  int h  = wid & 15;
  int d = lane, i = d & 31;

  size_t qoff = (size_t)(n0 + nl) * CDIM + h * 64 + d;
  float qv = q[qoff];
  float qp = __shfl_xor(qv, 32);
  float cq = cosT[12 * 32 + i], sq = sinT[12 * 32 + i];
  float qr = (d < 32) ? (qv * cq - qp * sq) : (qv * cq + qp * sq);

  const uint16_t* Kp = Kb + (size_t)nl * (LSEQ * CDIM) + h * 64 + d;
  const uint16_t* Vp = Vb + (size_t)nl * (LSEQ * CDIM) + h * 64 + d;

  float s[LSEQ];
#pragma unroll
  for (int m = 0; m < LSEQ; ++m){
    float kv = bf2f(Kp[m * CDIM]);
    float kp = __shfl_xor(kv, 32);
    float cm = cosT[m * 32 + i], sm = sinT[m * 32 + i];
    float kr = (d < 32) ? (kv * cm - kp * sm) : (kv * cm + kp * sm);
    float p = qr * kr;
    p += __shfl_xor(p, 32); p += __shfl_xor(p, 16); p += __shfl_xor(p, 8);
    p += __shfl_xor(p, 4);  p += __shfl_xor(p, 2);  p += __shfl_xor(p, 1);
    s[m] = p * 0.125f;
  }
  float mx = s[0];
#pragma unroll
  for (int m = 1; m < LSEQ; ++m) mx = fmaxf(mx, s[m]);
  float sum = 0.f;
#pragma unroll
  for (int m = 0; m < LSEQ; ++m){ s[m] = expf(s[m] - mx); sum += s[m]; }
  float inv = 1.0f / sum;
  float o = 0.f;
#pragma unroll
  for (int m = 0; m < LSEQ; ++m) o += s[m] * bf2f(Vp[m * CDIM]);
  o *= inv;
  uint16_t hb = f2bf(o);
  uint16_t lb = f2bf(o - bf2f(hb));
  ohi[qoff] = hb;
  olo[qoff] = lb;
}

// ---------------- host ----------------
extern "C" void kernel_launch(void* const* d_in, const int* in_sizes, int n_in,
                              void* d_out, int out_size, void* d_ws, size_t ws_size,
                              hipStream_t stream)
{
  (void)in_sizes; (void)n_in; (void)out_size;
  const float* src = (const float*)d_in[0];
  const float* Wq  = (const float*)d_in[1];
  const float* Wk  = (const float*)d_in[2];
  const float* Wv  = (const float*)d_in[3];
  const float* Wo  = (const float*)d_in[4];
  float* out = (float*)d_out;

  // adaptive chunk (cn multiple of 256 so cn*13 divides by 256-row tiles)
  int cn = 4096;
  while (cn > 256 && (55000000ull + (size_t)cn * 79872ull) > ws_size) cn >>= 1;
  const int nchunks = NTOK / cn;

  char* p = (char*)d_ws;
  auto carve = [&](size_t bytes) -> void* {
    void* r = (void*)p; p += (bytes + 255) & ~(size_t)255; return r;
  };
  uint16_t* W1q  = (uint16_t*)carve((size_t)CDIM * CDIM * 2);
  uint16_t* W1kv = (uint16_t*)carve((size_t)2 * CDIM * CDIM * 2);  // rows 0..1023 K, 1024..2047 V
  uint16_t* W1o  = (uint16_t*)carve((size_t)CDIM * CDIM * 2);
  float* cosT = (float*)carve(LSEQ * 32 * 4);
  float* sinT = (float*)carve(LSEQ * 32 * 4);
  uint16_t* Aqh = (uint16_t*)carve((size_t)NTOK * CDIM * 2);
  float* qbuf   = (float*)carve((size_t)NTOK * CDIM * 4);
  uint16_t* ohi = (uint16_t*)carve((size_t)NTOK * CDIM * 2);
  uint16_t* olo = (uint16_t*)carve((size_t)NTOK * CDIM * 2);
  uint16_t* Ah  = (uint16_t*)carve((size_t)cn * LSEQ * CDIM * 2);
  uint16_t* Kb  = (uint16_t*)carve((size_t)cn * LSEQ * CDIM * 2);
  uint16_t* Vb  = (uint16_t*)carve((size_t)cn * LSEQ * CDIM * 2);

  convert_W1<<<1024, 256, 0, stream>>>(Wq, W1q);
  convert_W1<<<1024, 256, 0, stream>>>(Wk, W1kv);
  convert_W1<<<1024, 256, 0, stream>>>(Wv, W1kv + (size_t)CDIM * CDIM);
  convert_W1<<<1024, 256, 0, stream>>>(Wo, W1o);
  rope_table<<<1, 512, 0, stream>>>(cosT, sinT);
  convert_Aq1<<<NTOK, 256, 0, stream>>>(src, Aqh);
  gemm128<16, false><<<dim3(NTOK / 128, 8), 256, 0, stream>>>(Aqh, nullptr, W1q, qbuf);

  for (int c = 0; c < nchunks; ++c){
    const int mt = cn * LSEQ / 256;       // 256-row tiles (208 at cn=4096)
    convert_A<<<cn * LSEQ, 256, 0, stream>>>(src, Ah, c * cn);
    gemm8_kv<<<dim3(8, mt), 512, 0, stream>>>(Ah, W1kv, Kb, Vb);
    attn_kernel<<<cn * 4, 256, 0, stream>>>(Kb, Vb, qbuf, cosT, sinT, ohi, olo, c * cn);
  }
  gemm128<32, true><<<dim3(NTOK / 128, 8), 256, 0, stream>>>(ohi, olo, W1o, out);
}